// Round 5
// baseline (542.986 us; speedup 1.0000x reference)
//
#include <hip/hip_runtime.h>

typedef __attribute__((ext_vector_type(8))) short short8;
typedef __attribute__((ext_vector_type(4))) float floatx4;

// ---------- bf16 helpers ----------
__device__ __forceinline__ float bf2f(unsigned short u) {
  union { unsigned int i; float f; } v; v.i = ((unsigned int)u) << 16; return v.f;
}
__device__ __forceinline__ unsigned short f2bf(float f) {
  union { float f; unsigned int i; } v; v.f = f;
  unsigned int x = v.i + 0x7fffu + ((v.i >> 16) & 1u);
  return (unsigned short)(x >> 16);
}
__device__ __forceinline__ float loadE(const void* p, size_t i, int f) {
  return f ? ((const float*)p)[i] : bf2f(((const unsigned short*)p)[i]);
}
__device__ __forceinline__ uint4 packbf(float4 a, float4 b) {
  union { unsigned short u[8]; uint4 v; } p;
  p.u[0] = f2bf(a.x); p.u[1] = f2bf(a.y); p.u[2] = f2bf(a.z); p.u[3] = f2bf(a.w);
  p.u[4] = f2bf(b.x); p.u[5] = f2bf(b.y); p.u[6] = f2bf(b.z); p.u[7] = f2bf(b.w);
  return p.v;
}

// ---------- dtype detect ----------
__global__ void detect_kernel(const unsigned int* __restrict__ probe, int* __restrict__ flag) {
  if (threadIdx.x == 0 && blockIdx.x == 0) *flag = (probe[0] == 0x3F800000u) ? 1 : 0;
}

// ---------- one-shot weight conversion: all 12 weight matrices -> bf16 ----------
struct CArgs {
  const void* in[12];
  unsigned short* out[12];
  unsigned int cum[12];  // cumulative chunk (8-elem) counts
};
__global__ __launch_bounds__(256) void convw_kernel(CArgs a, int total_chunks,
                                                    const int* __restrict__ flagp) {
  const int flag = *flagp;
  for (int c = blockIdx.x * 256 + threadIdx.x; c < total_chunks; c += gridDim.x * 256) {
    int s = 0;
    while (c >= (int)a.cum[s]) ++s;
    unsigned int base = s ? a.cum[s - 1] : 0u;
    size_t e = (size_t)(c - base) * 8;
    if (flag) {
      const float* in = (const float*)a.in[s] + e;
      float4 v0 = *(const float4*)in;
      float4 v1 = *(const float4*)(in + 4);
      *(uint4*)(a.out[s] + e) = packbf(v0, v1);
    } else {
      *(uint4*)(a.out[s] + e) = *(const uint4*)((const unsigned short*)a.in[s] + e);
    }
  }
}

// ---------- zero d_out (dtype-aware) ----------
__global__ __launch_bounds__(256) void zero_kernel(void* __restrict__ out, int out_elems,
                                                   const int* __restrict__ flagp) {
  int limit = (*flagp) ? (out_elems >> 2) : (out_elems >> 3);  // uint4 chunks
  int i = blockIdx.x * 256 + threadIdx.x;
  if (i < limit) ((uint4*)out)[i] = make_uint4(0, 0, 0, 0);
}

// ---------- LayerNorm over both external inputs -> unified bf16 (c rows first) ----------
__global__ __launch_bounds__(256) void ln_ext_kernel(const void* __restrict__ cin,
                                                     const void* __restrict__ xin,
                                                     unsigned short* __restrict__ out,
                                                     const int* __restrict__ flagp) {
  const int D = 1024, S = 512;
  const int flag = *flagp;
  int row = blockIdx.x;
  const void* src = (row < S) ? cin : xin;
  size_t rb = (size_t)(row < S ? row : row - S) * D;
  int base = threadIdx.x * 4;
  float x0 = loadE(src, rb + base + 0, flag);
  float x1 = loadE(src, rb + base + 1, flag);
  float x2 = loadE(src, rb + base + 2, flag);
  float x3 = loadE(src, rb + base + 3, flag);
  float s1 = x0 + x1 + x2 + x3;
  float s2 = x0 * x0 + x1 * x1 + x2 * x2 + x3 * x3;
  for (int off = 32; off; off >>= 1) {
    s1 += __shfl_down(s1, off, 64);
    s2 += __shfl_down(s2, off, 64);
  }
  __shared__ float red[8];
  int wid = threadIdx.x >> 6;
  if ((threadIdx.x & 63) == 0) { red[wid] = s1; red[4 + wid] = s2; }
  __syncthreads();
  s1 = red[0] + red[1] + red[2] + red[3];
  s2 = red[4] + red[5] + red[6] + red[7];
  float mean = s1 * (1.0f / D);
  float var = s2 * (1.0f / D) - mean * mean;
  float inv = rsqrtf(var + 1e-6f);
  unsigned short* dst = out + (size_t)row * D + base;
  dst[0] = f2bf((x0 - mean) * inv);
  dst[1] = f2bf((x1 - mean) * inv);
  dst[2] = f2bf((x2 - mean) * inv);
  dst[3] = f2bf((x3 - mean) * inv);
}

// ---------- LayerNorm over internal bf16 mid; split outputs ----------
__global__ __launch_bounds__(256) void ln_mid_kernel(const unsigned short* __restrict__ in,
                                                     unsigned short* __restrict__ outc,
                                                     unsigned short* __restrict__ outx) {
  const int D = 1024, S = 512;
  int row = blockIdx.x;
  const unsigned short* src = in + (size_t)row * D;
  int base = threadIdx.x * 4;
  float x0 = bf2f(src[base + 0]);
  float x1 = bf2f(src[base + 1]);
  float x2 = bf2f(src[base + 2]);
  float x3 = bf2f(src[base + 3]);
  float s1 = x0 + x1 + x2 + x3;
  float s2 = x0 * x0 + x1 * x1 + x2 * x2 + x3 * x3;
  for (int off = 32; off; off >>= 1) {
    s1 += __shfl_down(s1, off, 64);
    s2 += __shfl_down(s2, off, 64);
  }
  __shared__ float red[8];
  int wid = threadIdx.x >> 6;
  if ((threadIdx.x & 63) == 0) { red[wid] = s1; red[4 + wid] = s2; }
  __syncthreads();
  s1 = red[0] + red[1] + red[2] + red[3];
  s2 = red[4] + red[5] + red[6] + red[7];
  float mean = s1 * (1.0f / D);
  float var = s2 * (1.0f / D) - mean * mean;
  float inv = rsqrtf(var + 1e-6f);
  unsigned short* dst = (row < S ? outc + (size_t)row * D : outx + (size_t)(row - S) * D) + base;
  dst[0] = f2bf((x0 - mean) * inv);
  dst[1] = f2bf((x1 - mean) * inv);
  dst[2] = f2bf((x2 - mean) * inv);
  dst[3] = f2bf((x3 - mean) * inv);
}

// ---------- multi-descriptor GEMM ----------
// C[M,N] = A[M,K](bf16) @ B[N,K]^T. 128x128 tile, BK=32, 4 waves, 4x4 mfma,
// LDS double-buffer (pad 40 hw).
// BBF16=1 (workspace-converted bf16 weights): 2-DEEP register pipeline.
//   set0 holds even tiles, set1 odd tiles (16 VGPR each; affordable now that
//   the fp32 pack is hoisted out -- round-0's dual-dtype 2-deep spilled).
//   Iter t: store tile t+1 from its set (loaded 2 iters ago -> vmcnt wait is
//   covered by TWO compute phases + two barriers ~= HBM-miss latency), reload
//   that set with tile t+3, compute tile t, lgkm-only BAR. Loop unrolled x2 so
//   set indexing is static (rule #20). Round-4 counters showed the 1-deep
//   version left a ~500-700cyc vmcnt stall per tile (MfmaUtil 8.6%).
// BBF16=0 fallback: round-3 single-set loop (pack at load).
// RES_MODE: 0 none, 1 += external dual res, 3 out=silu(bf16 res)*(acc+bias), 4 += bf16 res.
// OUT_MODE: 0 internal bf16, 2 external dual. SPLITK>1 (OUT 2 only): fp32 atomicAdd slices
// (bias/res added by slice 0); bf16-out fallback: slice 0 does full K, others exit.
struct GArgs {
  const unsigned short* A[4];
  const void* B[4];
  const void* bias[4];
  const void* res[4];
  void* C[4];
  unsigned long long oo[4];
  int mcum[4];  // cumulative m-tile counts
  int N[4];
  int K;
  int nd;
};

// LDS-only fence + barrier: drains this wave's ds ops, NOT vmcnt, so in-flight
// global prefetch survives the barrier.
#define BAR() asm volatile("s_waitcnt lgkmcnt(0)\n\ts_barrier" ::: "memory")

template <int RES_MODE, int OUT_MODE, int SPLITK, int BBF16>
__global__ __launch_bounds__(256) void gemm_kernel(GArgs g, const int* __restrict__ flagp) {
  const int flag = *flagp;
  // descriptor select
  int by = blockIdx.y;
  int d = 0;
  while (d < g.nd - 1 && by >= g.mcum[d]) ++d;
  int mbase = (d == 0) ? 0 : g.mcum[d - 1];
  const int m0 = (by - mbase) * 128;
  const int N = g.N[d];
  const int n0 = blockIdx.x * 128;
  if (n0 >= N) return;  // block-uniform
  const int K = g.K;
  // K slice
  int kbeg = 0, kend = K;
  if (SPLITK > 1) {
    if (!flag) {
      if (blockIdx.z != 0) return;
    } else {
      int kl = K / SPLITK;
      kbeg = blockIdx.z * kl;
      kend = kbeg + kl;
    }
  }
  const int nt = (kend - kbeg) >> 5;

  __shared__ __align__(16) unsigned short sA[2 * 5120];  // 128 rows x 40 hw, 2 buffers
  __shared__ __align__(16) unsigned short sB[2 * 5120];

  const int tid = threadIdx.x;
  const int lane = tid & 63;
  const int wave = tid >> 6;
  const int wm = (wave >> 1) * 64, wn = (wave & 1) * 64;
  // staging assignment: chunk c in {tid, tid+256}; row=c>>2 (0..127), colblk=c&3 (8 hw)
  const int srow = tid >> 2;
  const int scol = (tid & 3) * 8;
  const int wo0 = srow * 40 + scol;
  const int wo1 = wo0 + 64 * 40;
  const unsigned short* Ag0 = g.A[d] + (size_t)(m0 + srow) * K + kbeg + scol;
  const unsigned short* Ag1 = Ag0 + (size_t)64 * K;
  const unsigned short* Bh0 = (const unsigned short*)g.B[d] + (size_t)(n0 + srow) * K + kbeg + scol;
  const unsigned short* Bh1 = Bh0 + (size_t)64 * K;
  const float* Bf0 = (const float*)g.B[d] + (size_t)(n0 + srow) * K + kbeg + scol;
  const float* Bf1 = Bf0 + (size_t)64 * K;

  const int fr = lane & 15, fc = (lane >> 4) * 8;
  floatx4 acc[4][4] = {};
  auto compute = [&](const unsigned short* as, const unsigned short* bs) {
    short8 af[4], bfr[4];
    #pragma unroll
    for (int i = 0; i < 4; ++i) {
      af[i]  = *(const short8*)(as + (wm + i * 16 + fr) * 40 + fc);
      bfr[i] = *(const short8*)(bs + (wn + i * 16 + fr) * 40 + fc);
    }
    #pragma unroll
    for (int mi = 0; mi < 4; ++mi)
      #pragma unroll
      for (int ni = 0; ni < 4; ++ni)
        acc[mi][ni] = __builtin_amdgcn_mfma_f32_16x16x32_bf16(af[mi], bfr[ni], acc[mi][ni], 0, 0, 0);
  };

  if (BBF16) {
    // ---- 2-deep pipelined path (pure bf16 staging) ----
    uint4 p0a0, p0a1, p0b0, p0b1;  // set0: even tiles
    uint4 p1a0, p1a1, p1b0, p1b1;  // set1: odd tiles
    auto ld0 = [&](int kk) {
      p0a0 = *(const uint4*)(Ag0 + kk); p0a1 = *(const uint4*)(Ag1 + kk);
      p0b0 = *(const uint4*)(Bh0 + kk); p0b1 = *(const uint4*)(Bh1 + kk);
    };
    auto ld1 = [&](int kk) {
      p1a0 = *(const uint4*)(Ag0 + kk); p1a1 = *(const uint4*)(Ag1 + kk);
      p1b0 = *(const uint4*)(Bh0 + kk); p1b1 = *(const uint4*)(Bh1 + kk);
    };
    auto st0 = [&](int buf) {
      unsigned short* sa = sA + buf * 5120;
      unsigned short* sb = sB + buf * 5120;
      *(uint4*)(sa + wo0) = p0a0; *(uint4*)(sa + wo1) = p0a1;
      *(uint4*)(sb + wo0) = p0b0; *(uint4*)(sb + wo1) = p0b1;
    };
    auto st1 = [&](int buf) {
      unsigned short* sa = sA + buf * 5120;
      unsigned short* sb = sB + buf * 5120;
      *(uint4*)(sa + wo0) = p1a0; *(uint4*)(sa + wo1) = p1a1;
      *(uint4*)(sb + wo0) = p1b0; *(uint4*)(sb + wo1) = p1b1;
    };
    // prologue: tile0 -> LDS0; tile1 -> set1; tile2 -> set0
    ld0(0);
    st0(0);
    if (nt > 1) ld1(32);
    if (nt > 2) ld0(64);
    BAR();
    for (int t = 0; t < nt; t += 2) {
      // body A (tile t, even): stage tile t+1 (set1), refill set1 with t+3
      if (t + 1 < nt) {
        st1(1);
        if (t + 3 < nt) ld1((t + 3) * 32);
      }
      compute(sA, sB);                    // buf0 = tile t
      if (t + 1 < nt) BAR();
      // body B (tile t+1, odd): stage tile t+2 (set0), refill set0 with t+4
      if (t + 2 < nt) {
        st0(0);
        if (t + 4 < nt) ld0((t + 4) * 32);
      }
      if (t + 1 < nt) compute(sA + 5120, sB + 5120);  // buf1 = tile t+1
      if (t + 2 < nt) BAR();
    }
  } else {
    // ---- fallback: round-3 single-set loop, dual dtype ----
    uint4 ra0, ra1, rb0, rb1;
    auto load_tile = [&](int kk) {
      ra0 = *(const uint4*)(Ag0 + kk);
      ra1 = *(const uint4*)(Ag1 + kk);
      if (!flag) {
        rb0 = *(const uint4*)(Bh0 + kk);
        rb1 = *(const uint4*)(Bh1 + kk);
      } else {
        float4 x0 = *(const float4*)(Bf0 + kk), x1 = *(const float4*)(Bf0 + kk + 4);
        float4 y0 = *(const float4*)(Bf1 + kk), y1 = *(const float4*)(Bf1 + kk + 4);
        rb0 = packbf(x0, x1);
        rb1 = packbf(y0, y1);
      }
    };
    auto store_tile = [&](int buf) {
      unsigned short* sa = sA + buf * 5120;
      unsigned short* sb = sB + buf * 5120;
      *(uint4*)(sa + wo0) = ra0;
      *(uint4*)(sa + wo1) = ra1;
      *(uint4*)(sb + wo0) = rb0;
      *(uint4*)(sb + wo1) = rb1;
    };
    load_tile(0);
    store_tile(0);
    if (nt > 1) load_tile(32);
    BAR();
    for (int t = 0; t < nt; ++t) {
      if (t + 1 < nt) {
        store_tile((t + 1) & 1);
        if (t + 2 < nt) load_tile((t + 2) * 32);
      }
      compute(sA + (t & 1) * 5120, sB + (t & 1) * 5120);
      if (t + 1 < nt) BAR();
    }
  }

  const void* bias = g.bias[d];
  const void* res = g.res[d];
  void* C = g.C[d];
  const size_t oo = g.oo[d];
  const bool first = (SPLITK <= 1) || (blockIdx.z == 0) || !flag;
  #pragma unroll
  for (int mi = 0; mi < 4; ++mi)
    #pragma unroll
    for (int ni = 0; ni < 4; ++ni)
      #pragma unroll
      for (int r = 0; r < 4; ++r) {
        int row = m0 + wm + mi * 16 + (lane >> 4) * 4 + r;
        int col = n0 + wn + ni * 16 + (lane & 15);
        float val = acc[mi][ni][r];
        size_t off = (size_t)row * N + col;
        if (first) {
          if (bias) val += loadE(bias, (size_t)col, flag);
          if (RES_MODE == 1) val += loadE(res, off, flag);
          if (RES_MODE == 3) {
            float h1v = bf2f(((const unsigned short*)res)[off]);
            val = (h1v / (1.0f + __expf(-h1v))) * val;
          }
          if (RES_MODE == 4) val += bf2f(((const unsigned short*)res)[off]);
        }
        if (OUT_MODE == 0) {
          ((unsigned short*)C)[off] = f2bf(val);
        } else {
          if (flag) {
            if (SPLITK > 1) atomicAdd((float*)C + oo + off, val);
            else            ((float*)C)[oo + off] = val;
          } else {
            ((unsigned short*)C)[oo + off] = f2bf(val);
          }
        }
      }
}

// ---------- per-(t,head) RMSNorm + RoPE, 4 heads/block, in place ----------
__global__ __launch_bounds__(256) void rmsrope_kernel(
    unsigned short* __restrict__ qk,
    const void* __restrict__ qn_c, const void* __restrict__ kn_c,
    const void* __restrict__ qn_x, const void* __restrict__ kn_x,
    const void* __restrict__ freqs, const int* __restrict__ flagp) {
  const int flag = *flagp;
  int t = blockIdx.x;
  int h = blockIdx.y * 4 + (threadIdx.x >> 6);
  int d = threadIdx.x & 63;
  unsigned short* qrow = qk + (size_t)t * 2048 + h * 64;
  unsigned short* krow = qrow + 1024;
  float q = bf2f(qrow[d]), k = bf2f(krow[d]);
  float qs = q * q, ks = k * k;
  for (int off = 32; off; off >>= 1) {
    qs += __shfl_xor(qs, off, 64);
    ks += __shfl_xor(ks, off, 64);
  }
  const void* qn = (t < 512) ? qn_c : qn_x;
  const void* kn = (t < 512) ? kn_c : kn_x;
  q = q * rsqrtf(qs * (1.0f / 64.0f) + 1e-6f) * loadE(qn, d, flag);
  k = k * rsqrtf(ks * (1.0f / 64.0f) + 1e-6f) * loadE(kn, d, flag);
  int j = d >> 1;
  float cv = loadE(freqs, (size_t)(t * 32 + j) * 2 + 0, flag);
  float sv = loadE(freqs, (size_t)(t * 32 + j) * 2 + 1, flag);
  float qo = __shfl_xor(q, 1, 64);
  float ko = __shfl_xor(k, 1, 64);
  float qn2, kn2;
  if ((d & 1) == 0) { qn2 = q * cv - qo * sv; kn2 = k * cv - ko * sv; }
  else              { qn2 = qo * sv + q * cv; kn2 = ko * sv + k * cv; }
  qrow[d] = f2bf(qn2);
  krow[d] = f2bf(kn2);
}

// ---------- MFMA flash attention: 64 Q-rows/block (4 waves x 16), 64-key tiles ----------
__global__ __launch_bounds__(256) void attn_kernel(const unsigned short* __restrict__ qk,
                                                   const unsigned short* __restrict__ v,
                                                   unsigned short* __restrict__ y) {
  int id = blockIdx.x;
  int blk = (id & 256) ? (31 - (id & 31)) : (id & 31);
  int h = (id >> 5) & 15;
  int wv = threadIdx.x >> 6;
  int lane = threadIdx.x & 63;
  int qbase = blk * 64 + wv * 16;

  __shared__ __align__(16) unsigned short Ks[64 * 72];
  __shared__ __align__(16) unsigned short Vt[64 * 64];
  __shared__ __align__(16) unsigned short ps[4][16 * 72];

  short8 qa[2];
  {
    int m = lane & 15, dj = (lane >> 4) * 8;
    const unsigned short* qp = qk + (size_t)(qbase + m) * 2048 + h * 64 + dj;
    qa[0] = *(const short8*)(qp);
    qa[1] = *(const short8*)(qp + 32);
  }
  floatx4 o[4] = {};
  float mrow[4] = {-1e30f, -1e30f, -1e30f, -1e30f};
  float lrow[4] = {0.f, 0.f, 0.f, 0.f};
  int ntiles = blk + 1;
  for (int tile = 0; tile < ntiles; ++tile) {
    int j0 = tile * 64;
    __syncthreads();
    for (int c2 = threadIdx.x; c2 < 512; c2 += 256) {
      int key = c2 >> 3, d0 = (c2 & 7) * 8;
      *(short8*)(Ks + key * 72 + d0) =
          *(const short8*)(qk + (size_t)(j0 + key) * 2048 + 1024 + h * 64 + d0);
      short8 vv = *(const short8*)(v + (size_t)(j0 + key) * 1024 + h * 64 + d0);
      int bphys = ((key >> 3) ^ (d0 >> 3)) * 8 + (key & 7);
      #pragma unroll
      for (int jj = 0; jj < 8; ++jj)
        Vt[(d0 + jj) * 64 + bphys] = ((const unsigned short*)&vv)[jj];
    }
    __syncthreads();
    floatx4 sacc[4];
    #pragma unroll
    for (int kg = 0; kg < 4; ++kg) {
      floatx4 z = {0.f, 0.f, 0.f, 0.f};
      #pragma unroll
      for (int kc = 0; kc < 2; ++kc) {
        short8 kb = *(const short8*)(Ks + (kg * 16 + (lane & 15)) * 72 + kc * 32 + (lane >> 4) * 8);
        z = __builtin_amdgcn_mfma_f32_16x16x32_bf16(qa[kc], kb, z, 0, 0, 0);
      }
      sacc[kg] = z;
    }
    #pragma unroll
    for (int kg = 0; kg < 4; ++kg)
      #pragma unroll
      for (int r = 0; r < 4; ++r) {
        int key_g = j0 + kg * 16 + (lane & 15);
        int q_g = qbase + (lane >> 4) * 4 + r;
        float s = sacc[kg][r] * 0.125f;
        sacc[kg][r] = (key_g <= q_g) ? s : -1e30f;
      }
    #pragma unroll
    for (int r = 0; r < 4; ++r) {
      float mx = fmaxf(fmaxf(sacc[0][r], sacc[1][r]), fmaxf(sacc[2][r], sacc[3][r]));
      mx = fmaxf(mx, __shfl_xor(mx, 1, 64));
      mx = fmaxf(mx, __shfl_xor(mx, 2, 64));
      mx = fmaxf(mx, __shfl_xor(mx, 4, 64));
      mx = fmaxf(mx, __shfl_xor(mx, 8, 64));
      float mnew = fmaxf(mrow[r], mx);
      float al = __expf(mrow[r] - mnew);
      mrow[r] = mnew;
      float sum = 0.f;
      #pragma unroll
      for (int kg = 0; kg < 4; ++kg) {
        float p = __expf(sacc[kg][r] - mnew);
        sacc[kg][r] = p;
        sum += p;
      }
      sum += __shfl_xor(sum, 1, 64);
      sum += __shfl_xor(sum, 2, 64);
      sum += __shfl_xor(sum, 4, 64);
      sum += __shfl_xor(sum, 8, 64);
      lrow[r] = lrow[r] * al + sum;
      #pragma unroll
      for (int ni = 0; ni < 4; ++ni) o[ni][r] *= al;
    }
    unsigned short* pw = ps[wv];
    #pragma unroll
    for (int kg = 0; kg < 4; ++kg)
      #pragma unroll
      for (int r = 0; r < 4; ++r)
        pw[((lane >> 4) * 4 + r) * 72 + kg * 16 + (lane & 15)] = f2bf(sacc[kg][r]);
    asm volatile("s_waitcnt lgkmcnt(0)" ::: "memory");
    short8 pa[2];
    pa[0] = *(const short8*)(pw + (lane & 15) * 72 + (lane >> 4) * 8);
    pa[1] = *(const short8*)(pw + (lane & 15) * 72 + 32 + (lane >> 4) * 8);
    #pragma unroll
    for (int ni = 0; ni < 4; ++ni) {
      floatx4 z = o[ni];
      int dd = ni * 16 + (lane & 15);
      #pragma unroll
      for (int kc = 0; kc < 2; ++kc) {
        int bphys = (kc * 4 + (lane >> 4)) ^ (dd >> 3);
        short8 vb = *(const short8*)(Vt + dd * 64 + bphys * 8);
        z = __builtin_amdgcn_mfma_f32_16x16x32_bf16(pa[kc], vb, z, 0, 0, 0);
      }
      o[ni] = z;
    }
  }
  #pragma unroll
  for (int ni = 0; ni < 4; ++ni)
    #pragma unroll
    for (int r = 0; r < 4; ++r) {
      int q = qbase + (lane >> 4) * 4 + r;
      int dd = ni * 16 + (lane & 15);
      y[(size_t)q * 1024 + h * 64 + dd] = f2bf(o[ni][r] / lrow[r]);
    }
}

extern "C" void kernel_launch(void* const* d_in, const int* in_sizes, int n_in,
                              void* d_out, int out_size, void* d_ws, size_t ws_size,
                              hipStream_t stream) {
  const int L = 1536, S = 512, D = 1024, T = 2048, FF = 4096;
  const void* x        = d_in[0];
  const void* c        = d_in[1];
  const void* freqs    = d_in[2];
  const void* px_qk_w  = d_in[3];
  const void* px_qn    = d_in[4];
  const void* px_kn    = d_in[5];
  const void* px_v_w   = d_in[6];
  const void* px_v_b   = d_in[7];
  const void* pc_qk_w  = d_in[8];
  const void* pc_qn    = d_in[9];
  const void* pc_kn    = d_in[10];
  const void* pc_v_w   = d_in[11];
  const void* pc_v_b   = d_in[12];
  const void* p1_proj_w = d_in[13];
  const void* p1_proj_b = d_in[14];
  const void* p1_w1 = d_in[15];
  const void* p1_b1 = d_in[16];
  const void* p1_w3 = d_in[17];
  const void* p1_b3 = d_in[18];
  const void* p1_w2 = d_in[19];
  const void* p1_b2 = d_in[20];
  const void* p2_proj_w = d_in[21];
  const void* p2_proj_b = d_in[22];
  const void* p2_w1 = d_in[23];
  const void* p2_b1 = d_in[24];
  const void* p2_w3 = d_in[25];
  const void* p2_b3 = d_in[26];
  const void* p2_w2 = d_in[27];
  const void* p2_b2 = d_in[28];

  // Workspace:
  //  [0,4)   hln -> ybuf (attn out) -> h1c (c-stream MLP hidden, 4 MiB)
  //  [4,12)  qk [T][2048]           -> (dead after attn)
  //  [12,16) v  [T][D]              -> (dead after attn)
  //  [4,16)  h1x (x-stream MLP hidden, exactly 12 MiB)
  //  [16,20) mid [T][D] bf16 (live to W2)
  //  [20,21) midln_c
  //  [21MB]  dtype flag
  //  [24,88) bf16-converted weights (only if ws_size >= 90 MB)
  //  midln_x = d_out[0,3MiB) scratch (consumed by W1/W3 before d_out is zeroed)
  char* ws = (char*)d_ws;
  unsigned short* hln     = (unsigned short*)(ws);
  unsigned short* ybuf    = (unsigned short*)(ws);
  unsigned short* h1c     = (unsigned short*)(ws);
  unsigned short* qkbuf   = (unsigned short*)(ws + ((size_t)4  << 20));
  unsigned short* h1x     = (unsigned short*)(ws + ((size_t)4  << 20));
  unsigned short* vbuf    = (unsigned short*)(ws + ((size_t)12 << 20));
  unsigned short* mid     = (unsigned short*)(ws + ((size_t)16 << 20));
  unsigned short* midln_c = (unsigned short*)(ws + ((size_t)20 << 20));
  int*            flag    = (int*)(ws + ((size_t)21 << 20));
  unsigned short* midln_x = (unsigned short*)d_out;
  unsigned short* hlnx    = hln + (size_t)S * D;

  // bf16 weight cache layout (element offsets from wbf)
  const bool conv = ws_size >= ((size_t)90 << 20);
  unsigned short* wbf = (unsigned short*)(ws + ((size_t)24 << 20));
  unsigned short* b_qk_c = wbf + 0;           // 2048x1024
  unsigned short* b_qk_x = wbf + 2097152;     // 2048x1024
  unsigned short* b_v_c  = wbf + 4194304;     // 1024x1024
  unsigned short* b_v_x  = wbf + 5242880;     // 1024x1024
  unsigned short* b_pj1  = wbf + 6291456;     // 1024x1024 (p1_proj_w)
  unsigned short* b_pj2  = wbf + 7340032;     // 1024x1024 (p2_proj_w)
  unsigned short* b_w1p1 = wbf + 8388608;     // 4096x1024
  unsigned short* b_w1p2 = wbf + 12582912;
  unsigned short* b_w3p1 = wbf + 16777216;
  unsigned short* b_w3p2 = wbf + 20971520;
  unsigned short* b_w2p1 = wbf + 25165824;    // 1024x4096
  unsigned short* b_w2p2 = wbf + 29360128;

  detect_kernel<<<1, 64, 0, stream>>>((const unsigned int*)px_qn, flag);

  if (conv) {
    CArgs ca;
    const void* ins[12]   = {pc_qk_w, px_qk_w, pc_v_w, px_v_w, p1_proj_w, p2_proj_w,
                             p1_w1, p2_w1, p1_w3, p2_w3, p1_w2, p2_w2};
    unsigned short* os[12] = {b_qk_c, b_qk_x, b_v_c, b_v_x, b_pj1, b_pj2,
                              b_w1p1, b_w1p2, b_w3p1, b_w3p2, b_w2p1, b_w2p2};
    unsigned int cnt[12]  = {262144, 262144, 131072, 131072, 131072, 131072,
                             524288, 524288, 524288, 524288, 524288, 524288};
    unsigned int cum = 0;
    for (int i = 0; i < 12; ++i) { ca.in[i] = ins[i]; ca.out[i] = os[i]; cum += cnt[i]; ca.cum[i] = cum; }
    convw_kernel<<<2048, 256, 0, stream>>>(ca, (int)cum, flag);
  }

  ln_ext_kernel<<<T, 256, 0, stream>>>(c, x, hln, flag);

  // P1: QKV (4 descriptors, one dispatch)
  {
    GArgs g = {};
    g.A[0] = hln;  g.bias[0] = nullptr; g.C[0] = qkbuf;                    g.mcum[0] = 4;  g.N[0] = 2048;
    g.A[1] = hlnx; g.bias[1] = nullptr; g.C[1] = qkbuf + (size_t)S * 2048; g.mcum[1] = 16; g.N[1] = 2048;
    g.A[2] = hln;  g.bias[2] = pc_v_b;  g.C[2] = vbuf;                     g.mcum[2] = 20; g.N[2] = 1024;
    g.A[3] = hlnx; g.bias[3] = px_v_b;  g.C[3] = vbuf + (size_t)S * D;     g.mcum[3] = 32; g.N[3] = 1024;
    g.K = 1024; g.nd = 4;
    if (conv) {
      g.B[0] = b_qk_c; g.B[1] = b_qk_x; g.B[2] = b_v_c; g.B[3] = b_v_x;
      gemm_kernel<0, 0, 1, 1><<<dim3(16, 32), 256, 0, stream>>>(g, flag);
    } else {
      g.B[0] = pc_qk_w; g.B[1] = px_qk_w; g.B[2] = pc_v_w; g.B[3] = px_v_w;
      gemm_kernel<0, 0, 1, 0><<<dim3(16, 32), 256, 0, stream>>>(g, flag);
    }
  }
  rmsrope_kernel<<<dim3(T, 4), 256, 0, stream>>>(qkbuf, pc_qn, pc_kn, px_qn, px_kn, freqs, flag);
  attn_kernel<<<512, 256, 0, stream>>>(qkbuf, vbuf, ybuf);

  // P2: out-projection + external residual -> mid
  {
    GArgs g = {};
    g.A[0] = ybuf;                  g.bias[0] = p2_proj_b; g.res[0] = c; g.C[0] = mid;                  g.mcum[0] = 4;  g.N[0] = 1024;
    g.A[1] = ybuf + (size_t)S * D;  g.bias[1] = p1_proj_b; g.res[1] = x; g.C[1] = mid + (size_t)S * D;  g.mcum[1] = 16; g.N[1] = 1024;
    g.K = 1024; g.nd = 2;
    if (conv) {
      g.B[0] = b_pj2; g.B[1] = b_pj1;
      gemm_kernel<1, 0, 1, 1><<<dim3(8, 16), 256, 0, stream>>>(g, flag);
    } else {
      g.B[0] = p2_proj_w; g.B[1] = p1_proj_w;
      gemm_kernel<1, 0, 1, 0><<<dim3(8, 16), 256, 0, stream>>>(g, flag);
    }
  }
  ln_mid_kernel<<<T, 256, 0, stream>>>(mid, midln_c, midln_x);

  // P3: W1 (x + c merged)
  {
    GArgs g = {};
    g.A[0] = midln_x; g.bias[0] = p1_b1; g.C[0] = h1x; g.mcum[0] = 12; g.N[0] = 4096;
    g.A[1] = midln_c; g.bias[1] = p2_b1; g.C[1] = h1c; g.mcum[1] = 16; g.N[1] = 4096;
    g.K = 1024; g.nd = 2;
    if (conv) {
      g.B[0] = b_w1p1; g.B[1] = b_w1p2;
      gemm_kernel<0, 0, 1, 1><<<dim3(32, 16), 256, 0, stream>>>(g, flag);
    } else {
      g.B[0] = p1_w1; g.B[1] = p2_w1;
      gemm_kernel<0, 0, 1, 0><<<dim3(32, 16), 256, 0, stream>>>(g, flag);
    }
  }
  // P4: W3 with fused silu(h1)*(acc+bias), in place
  {
    GArgs g = {};
    g.A[0] = midln_x; g.bias[0] = p1_b3; g.res[0] = h1x; g.C[0] = h1x; g.mcum[0] = 12; g.N[0] = 4096;
    g.A[1] = midln_c; g.bias[1] = p2_b3; g.res[1] = h1c; g.C[1] = h1c; g.mcum[1] = 16; g.N[1] = 4096;
    g.K = 1024; g.nd = 2;
    if (conv) {
      g.B[0] = b_w3p1; g.B[1] = b_w3p2;
      gemm_kernel<3, 0, 1, 1><<<dim3(32, 16), 256, 0, stream>>>(g, flag);
    } else {
      g.B[0] = p1_w3; g.B[1] = p2_w3;
      gemm_kernel<3, 0, 1, 0><<<dim3(32, 16), 256, 0, stream>>>(g, flag);
    }
  }
  // zero d_out, then P5: W2 split-K=4 atomics (+bias+res by slice 0)
  zero_kernel<<<2048, 256, 0, stream>>>(d_out, out_size, flag);
  {
    GArgs g = {};
    g.A[0] = h1x; g.bias[0] = p1_b2; g.res[0] = mid + (size_t)S * D; g.C[0] = d_out; g.oo[0] = 0;             g.mcum[0] = 12; g.N[0] = 1024;
    g.A[1] = h1c; g.bias[1] = p2_b2; g.res[1] = mid;                 g.C[1] = d_out; g.oo[1] = (size_t)L * D; g.mcum[1] = 16; g.N[1] = 1024;
    g.K = 4096; g.nd = 2;
    if (conv) {
      g.B[0] = b_w2p1; g.B[1] = b_w2p2;
      gemm_kernel<4, 2, 4, 1><<<dim3(8, 16, 4), 256, 0, stream>>>(g, flag);
    } else {
      g.B[0] = p1_w2; g.B[1] = p2_w2;
      gemm_kernel<4, 2, 4, 0><<<dim3(8, 16, 4), 256, 0, stream>>>(g, flag);
    }
  }
}

// Round 6
// 511.823 us; speedup vs baseline: 1.0609x; 1.0609x over previous
//
#include <hip/hip_runtime.h>

typedef __attribute__((ext_vector_type(8))) short short8;
typedef __attribute__((ext_vector_type(4))) float floatx4;

// ---------- bf16 helpers ----------
__device__ __forceinline__ float bf2f(unsigned short u) {
  union { unsigned int i; float f; } v; v.i = ((unsigned int)u) << 16; return v.f;
}
__device__ __forceinline__ unsigned short f2bf(float f) {
  union { float f; unsigned int i; } v; v.f = f;
  unsigned int x = v.i + 0x7fffu + ((v.i >> 16) & 1u);
  return (unsigned short)(x >> 16);
}
__device__ __forceinline__ float loadE(const void* p, size_t i, int f) {
  return f ? ((const float*)p)[i] : bf2f(((const unsigned short*)p)[i]);
}
__device__ __forceinline__ uint4 packbf(float4 a, float4 b) {
  union { unsigned short u[8]; uint4 v; } p;
  p.u[0] = f2bf(a.x); p.u[1] = f2bf(a.y); p.u[2] = f2bf(a.z); p.u[3] = f2bf(a.w);
  p.u[4] = f2bf(b.x); p.u[5] = f2bf(b.y); p.u[6] = f2bf(b.z); p.u[7] = f2bf(b.w);
  return p.v;
}

// async global->LDS, 16B per lane. LDS dest = wave-uniform base + lane*16.
__device__ __forceinline__ void gl16(const unsigned short* g, unsigned short* l) {
  __builtin_amdgcn_global_load_lds(
      (const __attribute__((address_space(1))) void*)g,
      (__attribute__((address_space(3))) void*)l, 16, 0, 0);
}

// ---------- dtype detect ----------
__global__ void detect_kernel(const unsigned int* __restrict__ probe, int* __restrict__ flag) {
  if (threadIdx.x == 0 && blockIdx.x == 0) *flag = (probe[0] == 0x3F800000u) ? 1 : 0;
}

// ---------- one-shot weight conversion: all 12 weight matrices -> bf16 ----------
struct CArgs {
  const void* in[12];
  unsigned short* out[12];
  unsigned int cum[12];  // cumulative chunk (8-elem) counts
};
__global__ __launch_bounds__(256) void convw_kernel(CArgs a, int total_chunks,
                                                    const int* __restrict__ flagp) {
  const int flag = *flagp;
  for (int c = blockIdx.x * 256 + threadIdx.x; c < total_chunks; c += gridDim.x * 256) {
    int s = 0;
    while (c >= (int)a.cum[s]) ++s;
    unsigned int base = s ? a.cum[s - 1] : 0u;
    size_t e = (size_t)(c - base) * 8;
    if (flag) {
      const float* in = (const float*)a.in[s] + e;
      float4 v0 = *(const float4*)in;
      float4 v1 = *(const float4*)(in + 4);
      *(uint4*)(a.out[s] + e) = packbf(v0, v1);
    } else {
      *(uint4*)(a.out[s] + e) = *(const uint4*)((const unsigned short*)a.in[s] + e);
    }
  }
}

// ---------- zero d_out (fallback path only) ----------
__global__ __launch_bounds__(256) void zero_kernel(void* __restrict__ out, int out_elems,
                                                   const int* __restrict__ flagp) {
  int limit = (*flagp) ? (out_elems >> 2) : (out_elems >> 3);  // uint4 chunks
  int i = blockIdx.x * 256 + threadIdx.x;
  if (i < limit) ((uint4*)out)[i] = make_uint4(0, 0, 0, 0);
}

// ---------- split-K partial reduce: d_out = sum_z part[z] + bias + res(mid) ----------
// fp32 path only (bf16 path writes d_out directly in the GEMM). 4 slices x 8MB.
__global__ __launch_bounds__(256) void reduce_kernel(const float* __restrict__ part,
                                                     const unsigned short* __restrict__ mid,
                                                     const void* __restrict__ b1,   // p1_b2 (x rows)
                                                     const void* __restrict__ b2,   // p2_b2 (c rows)
                                                     float* __restrict__ out,
                                                     const int* __restrict__ flagp) {
  if (!*flagp) return;
  const size_t TD = 2097152, LD = (size_t)1536 * 1024, SD = (size_t)512 * 1024;
  size_t i = ((size_t)blockIdx.x * 256 + threadIdx.x) * 4;
  if (i >= TD) return;
  float4 v  = *(const float4*)(part + i);
  float4 v1 = *(const float4*)(part + TD + i);
  float4 v2 = *(const float4*)(part + 2 * TD + i);
  float4 v3 = *(const float4*)(part + 3 * TD + i);
  v.x += v1.x + v2.x + v3.x;
  v.y += v1.y + v2.y + v3.y;
  v.z += v1.z + v2.z + v3.z;
  v.w += v1.w + v2.w + v3.w;
  int col = (int)(i & 1023);
  const float* bias = (const float*)((i < LD) ? b1 : b2);
  size_t ri = (i < LD) ? (SD + i) : (i - LD);
  v.x += bias[col + 0] + bf2f(mid[ri + 0]);
  v.y += bias[col + 1] + bf2f(mid[ri + 1]);
  v.z += bias[col + 2] + bf2f(mid[ri + 2]);
  v.w += bias[col + 3] + bf2f(mid[ri + 3]);
  *(float4*)(out + i) = v;
}

// ---------- LayerNorm over both external inputs -> unified bf16 (c rows first) ----------
__global__ __launch_bounds__(256) void ln_ext_kernel(const void* __restrict__ cin,
                                                     const void* __restrict__ xin,
                                                     unsigned short* __restrict__ out,
                                                     const int* __restrict__ flagp) {
  const int D = 1024, S = 512;
  const int flag = *flagp;
  int row = blockIdx.x;
  const void* src = (row < S) ? cin : xin;
  size_t rb = (size_t)(row < S ? row : row - S) * D;
  int base = threadIdx.x * 4;
  float x0 = loadE(src, rb + base + 0, flag);
  float x1 = loadE(src, rb + base + 1, flag);
  float x2 = loadE(src, rb + base + 2, flag);
  float x3 = loadE(src, rb + base + 3, flag);
  float s1 = x0 + x1 + x2 + x3;
  float s2 = x0 * x0 + x1 * x1 + x2 * x2 + x3 * x3;
  for (int off = 32; off; off >>= 1) {
    s1 += __shfl_down(s1, off, 64);
    s2 += __shfl_down(s2, off, 64);
  }
  __shared__ float red[8];
  int wid = threadIdx.x >> 6;
  if ((threadIdx.x & 63) == 0) { red[wid] = s1; red[4 + wid] = s2; }
  __syncthreads();
  s1 = red[0] + red[1] + red[2] + red[3];
  s2 = red[4] + red[5] + red[6] + red[7];
  float mean = s1 * (1.0f / D);
  float var = s2 * (1.0f / D) - mean * mean;
  float inv = rsqrtf(var + 1e-6f);
  unsigned short* dst = out + (size_t)row * D + base;
  dst[0] = f2bf((x0 - mean) * inv);
  dst[1] = f2bf((x1 - mean) * inv);
  dst[2] = f2bf((x2 - mean) * inv);
  dst[3] = f2bf((x3 - mean) * inv);
}

// ---------- LayerNorm over internal bf16 mid; split outputs ----------
__global__ __launch_bounds__(256) void ln_mid_kernel(const unsigned short* __restrict__ in,
                                                     unsigned short* __restrict__ outc,
                                                     unsigned short* __restrict__ outx) {
  const int D = 1024, S = 512;
  int row = blockIdx.x;
  const unsigned short* src = in + (size_t)row * D;
  int base = threadIdx.x * 4;
  float x0 = bf2f(src[base + 0]);
  float x1 = bf2f(src[base + 1]);
  float x2 = bf2f(src[base + 2]);
  float x3 = bf2f(src[base + 3]);
  float s1 = x0 + x1 + x2 + x3;
  float s2 = x0 * x0 + x1 * x1 + x2 * x2 + x3 * x3;
  for (int off = 32; off; off >>= 1) {
    s1 += __shfl_down(s1, off, 64);
    s2 += __shfl_down(s2, off, 64);
  }
  __shared__ float red[8];
  int wid = threadIdx.x >> 6;
  if ((threadIdx.x & 63) == 0) { red[wid] = s1; red[4 + wid] = s2; }
  __syncthreads();
  s1 = red[0] + red[1] + red[2] + red[3];
  s2 = red[4] + red[5] + red[6] + red[7];
  float mean = s1 * (1.0f / D);
  float var = s2 * (1.0f / D) - mean * mean;
  float inv = rsqrtf(var + 1e-6f);
  unsigned short* dst = (row < S ? outc + (size_t)row * D : outx + (size_t)(row - S) * D) + base;
  dst[0] = f2bf((x0 - mean) * inv);
  dst[1] = f2bf((x1 - mean) * inv);
  dst[2] = f2bf((x2 - mean) * inv);
  dst[3] = f2bf((x3 - mean) * inv);
}

// ---------- multi-descriptor GEMM ----------
// C[M,N] = A[M,K](bf16) @ B[N,K]^T. 128x128 tile, BK=32, 4 waves, 4x4 mfma.
// BBF16=1 (bf16 weight cache): global_load_lds staging (m97/T3 minimum 2-phase).
//   LDS layout [128][32]hw LINEAR (gload_lds needs contiguous lane x 16B dest).
//   Bank fix (rule #21, both-sides involution): physical 16B chunk p at row r holds
//   logical chunk p ^ ((r>>1)&3); store side pre-swizzles the GLOBAL source column,
//   read side XORs the chunk index -> 16-row read groups land 2 lanes/bank (free).
//   Loop: STAGE(buf^1, t+1) -> compute(buf) -> vmcnt(0)+lgkm+barrier (one per tile).
//   Round-5 showed reg-staging depth is NOT the lever (2-deep neutral); the VGPR
//   round-trip + ds_write machinery was the cost. gload_lds removes it (m151 +35%).
// BBF16=0 fallback: round-3 reg-staged loop (pack at load), pitch-40 LDS.
// RES_MODE: 0 none, 1 += external dual res, 3 out=silu(bf16 res)*(acc+bias), 4 += bf16 res.
// OUT_MODE: 0 internal bf16; 2 external dual + splitK atomics (fallback);
//           3 splitK raw fp32 partials to g.part (flag=1; bias/res in reduce_kernel),
//             bf16 direct for flag=0 (slice 0 full K).
struct GArgs {
  const unsigned short* A[4];
  const void* B[4];
  const void* bias[4];
  const void* res[4];
  void* C[4];
  unsigned long long oo[4];
  int mcum[4];  // cumulative m-tile counts
  int N[4];
  int K;
  int nd;
  float* part;  // split-K partial base (OUT_MODE 3), slice stride 2048*1024
};

// LDS-only fence + barrier (fallback path: global prefetch survives).
#define BAR() asm volatile("s_waitcnt lgkmcnt(0)\n\ts_barrier" ::: "memory")
// full drain + barrier (gload_lds path: next iter reads the freshly DMA'd buffer).
#define FBAR() asm volatile("s_waitcnt vmcnt(0) lgkmcnt(0)\n\ts_barrier" ::: "memory")

template <int RES_MODE, int OUT_MODE, int SPLITK, int BBF16>
__global__ __launch_bounds__(256) void gemm_kernel(GArgs g, const int* __restrict__ flagp) {
  const int flag = *flagp;
  // descriptor select
  int by = blockIdx.y;
  int d = 0;
  while (d < g.nd - 1 && by >= g.mcum[d]) ++d;
  int mbase = (d == 0) ? 0 : g.mcum[d - 1];
  const int m0 = (by - mbase) * 128;
  const int N = g.N[d];
  const int n0 = blockIdx.x * 128;
  if (n0 >= N) return;  // block-uniform
  const int K = g.K;
  // K slice
  int kbeg = 0, kend = K;
  if (SPLITK > 1) {
    if (!flag) {
      if (blockIdx.z != 0) return;
    } else {
      int kl = K / SPLITK;
      kbeg = blockIdx.z * kl;
      kend = kbeg + kl;
    }
  }
  const int nt = (kend - kbeg) >> 5;

  constexpr int BSTRIDE = BBF16 ? 4096 : 5120;  // hw elems per buffer
  __shared__ __align__(16) unsigned short sA[2 * BSTRIDE];
  __shared__ __align__(16) unsigned short sB[2 * BSTRIDE];

  const int tid = threadIdx.x;
  const int lane = tid & 63;
  const int wave = tid >> 6;
  const int wm = (wave >> 1) * 64, wn = (wave & 1) * 64;
  // staging: chunk c in {tid, tid+256}; row = c>>2 (0..127), 16B chunk slot = c&3.
  // BBF16: source column pre-swizzled so linear DMA dest realizes the XOR layout.
  const int srow = tid >> 2;
  const int scol = BBF16 ? ((((tid & 3) ^ ((tid >> 3) & 3))) * 8) : ((tid & 3) * 8);
  const unsigned short* Ag0 = g.A[d] + (size_t)(m0 + srow) * K + kbeg + scol;
  const unsigned short* Ag1 = Ag0 + (size_t)64 * K;
  const unsigned short* Bh0 = (const unsigned short*)g.B[d] + (size_t)(n0 + srow) * K + kbeg + scol;
  const unsigned short* Bh1 = Bh0 + (size_t)64 * K;

  const int fr = lane & 15;
  // read-side chunk swizzle: f(row) = (row>>1)&3 reduces to (fr>>1)&3 here
  const int rdo = BBF16 ? ((((lane >> 4) ^ ((fr >> 1) & 3))) * 8) : ((lane >> 4) * 8);
  constexpr int PITCH = BBF16 ? 32 : 40;
  floatx4 acc[4][4] = {};
  auto compute = [&](const unsigned short* as, const unsigned short* bs) {
    short8 af[4], bfr[4];
    #pragma unroll
    for (int i = 0; i < 4; ++i) {
      af[i]  = *(const short8*)(as + (wm + i * 16 + fr) * PITCH + rdo);
      bfr[i] = *(const short8*)(bs + (wn + i * 16 + fr) * PITCH + rdo);
    }
    #pragma unroll
    for (int mi = 0; mi < 4; ++mi)
      #pragma unroll
      for (int ni = 0; ni < 4; ++ni)
        acc[mi][ni] = __builtin_amdgcn_mfma_f32_16x16x32_bf16(af[mi], bfr[ni], acc[mi][ni], 0, 0, 0);
  };

  if (BBF16) {
    // ---- global_load_lds 2-phase path ----
    unsigned short* lA0 = sA + wave * 512;   // wave-uniform dest, lane*16B implicit
    unsigned short* lA1 = lA0 + 2048;        // rows 64..127
    unsigned short* lB0 = sB + wave * 512;
    unsigned short* lB1 = lB0 + 2048;
    auto stage = [&](int buf, int kk) {
      int bo = buf * 4096;
      gl16(Ag0 + kk, lA0 + bo);
      gl16(Ag1 + kk, lA1 + bo);
      gl16(Bh0 + kk, lB0 + bo);
      gl16(Bh1 + kk, lB1 + bo);
    };
    stage(0, 0);
    FBAR();
    for (int t = 0; t < nt; ++t) {
      if (t + 1 < nt) stage((t + 1) & 1, (t + 1) * 32);
      compute(sA + (t & 1) * 4096, sB + (t & 1) * 4096);
      if (t + 1 < nt) FBAR();
    }
  } else {
    // ---- fallback: reg-staged loop, dual dtype ----
    const float* Bf0 = (const float*)g.B[d] + (size_t)(n0 + srow) * K + kbeg + scol;
    const float* Bf1 = Bf0 + (size_t)64 * K;
    const int wo0 = srow * 40 + scol;
    const int wo1 = wo0 + 64 * 40;
    uint4 ra0, ra1, rb0, rb1;
    auto load_tile = [&](int kk) {
      ra0 = *(const uint4*)(Ag0 + kk);
      ra1 = *(const uint4*)(Ag1 + kk);
      if (!flag) {
        rb0 = *(const uint4*)(Bh0 + kk);
        rb1 = *(const uint4*)(Bh1 + kk);
      } else {
        float4 x0 = *(const float4*)(Bf0 + kk), x1 = *(const float4*)(Bf0 + kk + 4);
        float4 y0 = *(const float4*)(Bf1 + kk), y1 = *(const float4*)(Bf1 + kk + 4);
        rb0 = packbf(x0, x1);
        rb1 = packbf(y0, y1);
      }
    };
    auto store_tile = [&](int buf) {
      unsigned short* sa = sA + buf * 5120;
      unsigned short* sb = sB + buf * 5120;
      *(uint4*)(sa + wo0) = ra0;
      *(uint4*)(sa + wo1) = ra1;
      *(uint4*)(sb + wo0) = rb0;
      *(uint4*)(sb + wo1) = rb1;
    };
    load_tile(0);
    store_tile(0);
    if (nt > 1) load_tile(32);
    BAR();
    for (int t = 0; t < nt; ++t) {
      if (t + 1 < nt) {
        store_tile((t + 1) & 1);
        if (t + 2 < nt) load_tile((t + 2) * 32);
      }
      compute(sA + (t & 1) * 5120, sB + (t & 1) * 5120);
      if (t + 1 < nt) BAR();
    }
  }

  const void* bias = g.bias[d];
  const void* res = g.res[d];
  void* C = g.C[d];
  const size_t oo = g.oo[d];
  const bool first = (SPLITK <= 1) || (blockIdx.z == 0) || !flag;
  const bool rawpart = (OUT_MODE == 3) && (flag != 0);
  #pragma unroll
  for (int mi = 0; mi < 4; ++mi)
    #pragma unroll
    for (int ni = 0; ni < 4; ++ni)
      #pragma unroll
      for (int r = 0; r < 4; ++r) {
        int row = m0 + wm + mi * 16 + (lane >> 4) * 4 + r;
        int col = n0 + wn + ni * 16 + (lane & 15);
        float val = acc[mi][ni][r];
        size_t off = (size_t)row * N + col;
        if (first && !rawpart) {
          if (bias) val += loadE(bias, (size_t)col, flag);
          if (RES_MODE == 1) val += loadE(res, off, flag);
          if (RES_MODE == 3) {
            float h1v = bf2f(((const unsigned short*)res)[off]);
            val = (h1v / (1.0f + __expf(-h1v))) * val;
          }
          if (RES_MODE == 4) val += bf2f(((const unsigned short*)res)[off]);
        }
        if (OUT_MODE == 0) {
          ((unsigned short*)C)[off] = f2bf(val);
        } else if (OUT_MODE == 3) {
          if (flag) g.part[(size_t)blockIdx.z * 2097152 + oo + off] = val;
          else      ((unsigned short*)C)[oo + off] = f2bf(val);
        } else {  // OUT_MODE == 2 (fallback)
          if (flag) {
            if (SPLITK > 1) atomicAdd((float*)C + oo + off, val);
            else            ((float*)C)[oo + off] = val;
          } else {
            ((unsigned short*)C)[oo + off] = f2bf(val);
          }
        }
      }
}

// ---------- per-(t,head) RMSNorm + RoPE, 4 heads/block, in place ----------
__global__ __launch_bounds__(256) void rmsrope_kernel(
    unsigned short* __restrict__ qk,
    const void* __restrict__ qn_c, const void* __restrict__ kn_c,
    const void* __restrict__ qn_x, const void* __restrict__ kn_x,
    const void* __restrict__ freqs, const int* __restrict__ flagp) {
  const int flag = *flagp;
  int t = blockIdx.x;
  int h = blockIdx.y * 4 + (threadIdx.x >> 6);
  int d = threadIdx.x & 63;
  unsigned short* qrow = qk + (size_t)t * 2048 + h * 64;
  unsigned short* krow = qrow + 1024;
  float q = bf2f(qrow[d]), k = bf2f(krow[d]);
  float qs = q * q, ks = k * k;
  for (int off = 32; off; off >>= 1) {
    qs += __shfl_xor(qs, off, 64);
    ks += __shfl_xor(ks, off, 64);
  }
  const void* qn = (t < 512) ? qn_c : qn_x;
  const void* kn = (t < 512) ? kn_c : kn_x;
  q = q * rsqrtf(qs * (1.0f / 64.0f) + 1e-6f) * loadE(qn, d, flag);
  k = k * rsqrtf(ks * (1.0f / 64.0f) + 1e-6f) * loadE(kn, d, flag);
  int j = d >> 1;
  float cv = loadE(freqs, (size_t)(t * 32 + j) * 2 + 0, flag);
  float sv = loadE(freqs, (size_t)(t * 32 + j) * 2 + 1, flag);
  float qo = __shfl_xor(q, 1, 64);
  float ko = __shfl_xor(k, 1, 64);
  float qn2, kn2;
  if ((d & 1) == 0) { qn2 = q * cv - qo * sv; kn2 = k * cv - ko * sv; }
  else              { qn2 = qo * sv + q * cv; kn2 = ko * sv + k * cv; }
  qrow[d] = f2bf(qn2);
  krow[d] = f2bf(kn2);
}

// ---------- MFMA flash attention: 64 Q-rows/block (4 waves x 16), 64-key tiles ----------
__global__ __launch_bounds__(256) void attn_kernel(const unsigned short* __restrict__ qk,
                                                   const unsigned short* __restrict__ v,
                                                   unsigned short* __restrict__ y) {
  int id = blockIdx.x;
  int blk = (id & 256) ? (31 - (id & 31)) : (id & 31);
  int h = (id >> 5) & 15;
  int wv = threadIdx.x >> 6;
  int lane = threadIdx.x & 63;
  int qbase = blk * 64 + wv * 16;

  __shared__ __align__(16) unsigned short Ks[64 * 72];
  __shared__ __align__(16) unsigned short Vt[64 * 64];
  __shared__ __align__(16) unsigned short ps[4][16 * 72];

  short8 qa[2];
  {
    int m = lane & 15, dj = (lane >> 4) * 8;
    const unsigned short* qp = qk + (size_t)(qbase + m) * 2048 + h * 64 + dj;
    qa[0] = *(const short8*)(qp);
    qa[1] = *(const short8*)(qp + 32);
  }
  floatx4 o[4] = {};
  float mrow[4] = {-1e30f, -1e30f, -1e30f, -1e30f};
  float lrow[4] = {0.f, 0.f, 0.f, 0.f};
  int ntiles = blk + 1;
  for (int tile = 0; tile < ntiles; ++tile) {
    int j0 = tile * 64;
    __syncthreads();
    for (int c2 = threadIdx.x; c2 < 512; c2 += 256) {
      int key = c2 >> 3, d0 = (c2 & 7) * 8;
      *(short8*)(Ks + key * 72 + d0) =
          *(const short8*)(qk + (size_t)(j0 + key) * 2048 + 1024 + h * 64 + d0);
      short8 vv = *(const short8*)(v + (size_t)(j0 + key) * 1024 + h * 64 + d0);
      int bphys = ((key >> 3) ^ (d0 >> 3)) * 8 + (key & 7);
      #pragma unroll
      for (int jj = 0; jj < 8; ++jj)
        Vt[(d0 + jj) * 64 + bphys] = ((const unsigned short*)&vv)[jj];
    }
    __syncthreads();
    floatx4 sacc[4];
    #pragma unroll
    for (int kg = 0; kg < 4; ++kg) {
      floatx4 z = {0.f, 0.f, 0.f, 0.f};
      #pragma unroll
      for (int kc = 0; kc < 2; ++kc) {
        short8 kb = *(const short8*)(Ks + (kg * 16 + (lane & 15)) * 72 + kc * 32 + (lane >> 4) * 8);
        z = __builtin_amdgcn_mfma_f32_16x16x32_bf16(qa[kc], kb, z, 0, 0, 0);
      }
      sacc[kg] = z;
    }
    #pragma unroll
    for (int kg = 0; kg < 4; ++kg)
      #pragma unroll
      for (int r = 0; r < 4; ++r) {
        int key_g = j0 + kg * 16 + (lane & 15);
        int q_g = qbase + (lane >> 4) * 4 + r;
        float s = sacc[kg][r] * 0.125f;
        sacc[kg][r] = (key_g <= q_g) ? s : -1e30f;
      }
    #pragma unroll
    for (int r = 0; r < 4; ++r) {
      float mx = fmaxf(fmaxf(sacc[0][r], sacc[1][r]), fmaxf(sacc[2][r], sacc[3][r]));
      mx = fmaxf(mx, __shfl_xor(mx, 1, 64));
      mx = fmaxf(mx, __shfl_xor(mx, 2, 64));
      mx = fmaxf(mx, __shfl_xor(mx, 4, 64));
      mx = fmaxf(mx, __shfl_xor(mx, 8, 64));
      float mnew = fmaxf(mrow[r], mx);
      float al = __expf(mrow[r] - mnew);
      mrow[r] = mnew;
      float sum = 0.f;
      #pragma unroll
      for (int kg = 0; kg < 4; ++kg) {
        float p = __expf(sacc[kg][r] - mnew);
        sacc[kg][r] = p;
        sum += p;
      }
      sum += __shfl_xor(sum, 1, 64);
      sum += __shfl_xor(sum, 2, 64);
      sum += __shfl_xor(sum, 4, 64);
      sum += __shfl_xor(sum, 8, 64);
      lrow[r] = lrow[r] * al + sum;
      #pragma unroll
      for (int ni = 0; ni < 4; ++ni) o[ni][r] *= al;
    }
    unsigned short* pw = ps[wv];
    #pragma unroll
    for (int kg = 0; kg < 4; ++kg)
      #pragma unroll
      for (int r = 0; r < 4; ++r)
        pw[((lane >> 4) * 4 + r) * 72 + kg * 16 + (lane & 15)] = f2bf(sacc[kg][r]);
    asm volatile("s_waitcnt lgkmcnt(0)" ::: "memory");
    short8 pa[2];
    pa[0] = *(const short8*)(pw + (lane & 15) * 72 + (lane >> 4) * 8);
    pa[1] = *(const short8*)(pw + (lane & 15) * 72 + 32 + (lane >> 4) * 8);
    #pragma unroll
    for (int ni = 0; ni < 4; ++ni) {
      floatx4 z = o[ni];
      int dd = ni * 16 + (lane & 15);
      #pragma unroll
      for (int kc = 0; kc < 2; ++kc) {
        int bphys = (kc * 4 + (lane >> 4)) ^ (dd >> 3);
        short8 vb = *(const short8*)(Vt + dd * 64 + bphys * 8);
        z = __builtin_amdgcn_mfma_f32_16x16x32_bf16(pa[kc], vb, z, 0, 0, 0);
      }
      o[ni] = z;
    }
  }
  #pragma unroll
  for (int ni = 0; ni < 4; ++ni)
    #pragma unroll
    for (int r = 0; r < 4; ++r) {
      int q = qbase + (lane >> 4) * 4 + r;
      int dd = ni * 16 + (lane & 15);
      y[(size_t)q * 1024 + h * 64 + dd] = f2bf(o[ni][r] / lrow[r]);
    }
}

extern "C" void kernel_launch(void* const* d_in, const int* in_sizes, int n_in,
                              void* d_out, int out_size, void* d_ws, size_t ws_size,
                              hipStream_t stream) {
  const int L = 1536, S = 512, D = 1024, T = 2048, FF = 4096;
  const void* x        = d_in[0];
  const void* c        = d_in[1];
  const void* freqs    = d_in[2];
  const void* px_qk_w  = d_in[3];
  const void* px_qn    = d_in[4];
  const void* px_kn    = d_in[5];
  const void* px_v_w   = d_in[6];
  const void* px_v_b   = d_in[7];
  const void* pc_qk_w  = d_in[8];
  const void* pc_qn    = d_in[9];
  const void* pc_kn    = d_in[10];
  const void* pc_v_w   = d_in[11];
  const void* pc_v_b   = d_in[12];
  const void* p1_proj_w = d_in[13];
  const void* p1_proj_b = d_in[14];
  const void* p1_w1 = d_in[15];
  const void* p1_b1 = d_in[16];
  const void* p1_w3 = d_in[17];
  const void* p1_b3 = d_in[18];
  const void* p1_w2 = d_in[19];
  const void* p1_b2 = d_in[20];
  const void* p2_proj_w = d_in[21];
  const void* p2_proj_b = d_in[22];
  const void* p2_w1 = d_in[23];
  const void* p2_b1 = d_in[24];
  const void* p2_w3 = d_in[25];
  const void* p2_b3 = d_in[26];
  const void* p2_w2 = d_in[27];
  const void* p2_b2 = d_in[28];

  // Workspace:
  //  [0,4)   hln -> ybuf (attn out) -> h1c (c-stream MLP hidden, 4 MiB)
  //  [4,12)  qk [T][2048]           -> (dead after attn)
  //  [12,16) v  [T][D]              -> (dead after attn)
  //  [4,16)  h1x (x-stream MLP hidden, exactly 12 MiB)
  //  [16,20) mid [T][D] bf16 (live to W2)
  //  [20,21) midln_c
  //  [21MB]  dtype flag
  //  [24,88) bf16-converted weights (only if ws_size >= 90 MB)
  //          [40,72) = b_w1p1..b_w3p2 region -> REUSED as P5 fp32 partials (dead after P4)
  //  midln_x = d_out[0,3MiB) scratch (consumed by W1/W3 before d_out is written)
  char* ws = (char*)d_ws;
  unsigned short* hln     = (unsigned short*)(ws);
  unsigned short* ybuf    = (unsigned short*)(ws);
  unsigned short* h1c     = (unsigned short*)(ws);
  unsigned short* qkbuf   = (unsigned short*)(ws + ((size_t)4  << 20));
  unsigned short* h1x     = (unsigned short*)(ws + ((size_t)4  << 20));
  unsigned short* vbuf    = (unsigned short*)(ws + ((size_t)12 << 20));
  unsigned short* mid     = (unsigned short*)(ws + ((size_t)16 << 20));
  unsigned short* midln_c = (unsigned short*)(ws + ((size_t)20 << 20));
  int*            flag    = (int*)(ws + ((size_t)21 << 20));
  unsigned short* midln_x = (unsigned short*)d_out;
  unsigned short* hlnx    = hln + (size_t)S * D;

  // bf16 weight cache layout (element offsets from wbf)
  const bool conv = ws_size >= ((size_t)90 << 20);
  unsigned short* wbf = (unsigned short*)(ws + ((size_t)24 << 20));
  unsigned short* b_qk_c = wbf + 0;           // 2048x1024
  unsigned short* b_qk_x = wbf + 2097152;     // 2048x1024
  unsigned short* b_v_c  = wbf + 4194304;     // 1024x1024
  unsigned short* b_v_x  = wbf + 5242880;     // 1024x1024
  unsigned short* b_pj1  = wbf + 6291456;     // 1024x1024 (p1_proj_w)
  unsigned short* b_pj2  = wbf + 7340032;     // 1024x1024 (p2_proj_w)
  unsigned short* b_w1p1 = wbf + 8388608;     // 4096x1024  (@ws+40MB)
  unsigned short* b_w1p2 = wbf + 12582912;
  unsigned short* b_w3p1 = wbf + 16777216;
  unsigned short* b_w3p2 = wbf + 20971520;
  unsigned short* b_w2p1 = wbf + 25165824;    // 1024x4096
  unsigned short* b_w2p2 = wbf + 29360128;
  float* part = (float*)(ws + ((size_t)40 << 20));  // 4 x 8MB, overlays w1/w3 cache

  detect_kernel<<<1, 64, 0, stream>>>((const unsigned int*)px_qn, flag);

  if (conv) {
    CArgs ca;
    const void* ins[12]   = {pc_qk_w, px_qk_w, pc_v_w, px_v_w, p1_proj_w, p2_proj_w,
                             p1_w1, p2_w1, p1_w3, p2_w3, p1_w2, p2_w2};
    unsigned short* os[12] = {b_qk_c, b_qk_x, b_v_c, b_v_x, b_pj1, b_pj2,
                              b_w1p1, b_w1p2, b_w3p1, b_w3p2, b_w2p1, b_w2p2};
    unsigned int cnt[12]  = {262144, 262144, 131072, 131072, 131072, 131072,
                             524288, 524288, 524288, 524288, 524288, 524288};
    unsigned int cum = 0;
    for (int i = 0; i < 12; ++i) { ca.in[i] = ins[i]; ca.out[i] = os[i]; cum += cnt[i]; ca.cum[i] = cum; }
    convw_kernel<<<2048, 256, 0, stream>>>(ca, (int)cum, flag);
  }

  ln_ext_kernel<<<T, 256, 0, stream>>>(c, x, hln, flag);

  // P1: QKV (4 descriptors, one dispatch)
  {
    GArgs g = {};
    g.A[0] = hln;  g.bias[0] = nullptr; g.C[0] = qkbuf;                    g.mcum[0] = 4;  g.N[0] = 2048;
    g.A[1] = hlnx; g.bias[1] = nullptr; g.C[1] = qkbuf + (size_t)S * 2048; g.mcum[1] = 16; g.N[1] = 2048;
    g.A[2] = hln;  g.bias[2] = pc_v_b;  g.C[2] = vbuf;                     g.mcum[2] = 20; g.N[2] = 1024;
    g.A[3] = hlnx; g.bias[3] = px_v_b;  g.C[3] = vbuf + (size_t)S * D;     g.mcum[3] = 32; g.N[3] = 1024;
    g.K = 1024; g.nd = 4;
    if (conv) {
      g.B[0] = b_qk_c; g.B[1] = b_qk_x; g.B[2] = b_v_c; g.B[3] = b_v_x;
      gemm_kernel<0, 0, 1, 1><<<dim3(16, 32), 256, 0, stream>>>(g, flag);
    } else {
      g.B[0] = pc_qk_w; g.B[1] = px_qk_w; g.B[2] = pc_v_w; g.B[3] = px_v_w;
      gemm_kernel<0, 0, 1, 0><<<dim3(16, 32), 256, 0, stream>>>(g, flag);
    }
  }
  rmsrope_kernel<<<dim3(T, 4), 256, 0, stream>>>(qkbuf, pc_qn, pc_kn, px_qn, px_kn, freqs, flag);
  attn_kernel<<<512, 256, 0, stream>>>(qkbuf, vbuf, ybuf);

  // P2: out-projection + external residual -> mid
  {
    GArgs g = {};
    g.A[0] = ybuf;                  g.bias[0] = p2_proj_b; g.res[0] = c; g.C[0] = mid;                  g.mcum[0] = 4;  g.N[0] = 1024;
    g.A[1] = ybuf + (size_t)S * D;  g.bias[1] = p1_proj_b; g.res[1] = x; g.C[1] = mid + (size_t)S * D;  g.mcum[1] = 16; g.N[1] = 1024;
    g.K = 1024; g.nd = 2;
    if (conv) {
      g.B[0] = b_pj2; g.B[1] = b_pj1;
      gemm_kernel<1, 0, 1, 1><<<dim3(8, 16), 256, 0, stream>>>(g, flag);
    } else {
      g.B[0] = p2_proj_w; g.B[1] = p1_proj_w;
      gemm_kernel<1, 0, 1, 0><<<dim3(8, 16), 256, 0, stream>>>(g, flag);
    }
  }
  ln_mid_kernel<<<T, 256, 0, stream>>>(mid, midln_c, midln_x);

  // P3: W1 (x + c merged)
  {
    GArgs g = {};
    g.A[0] = midln_x; g.bias[0] = p1_b1; g.C[0] = h1x; g.mcum[0] = 12; g.N[0] = 4096;
    g.A[1] = midln_c; g.bias[1] = p2_b1; g.C[1] = h1c; g.mcum[1] = 16; g.N[1] = 4096;
    g.K = 1024; g.nd = 2;
    if (conv) {
      g.B[0] = b_w1p1; g.B[1] = b_w1p2;
      gemm_kernel<0, 0, 1, 1><<<dim3(32, 16), 256, 0, stream>>>(g, flag);
    } else {
      g.B[0] = p1_w1; g.B[1] = p2_w1;
      gemm_kernel<0, 0, 1, 0><<<dim3(32, 16), 256, 0, stream>>>(g, flag);
    }
  }
  // P4: W3 with fused silu(h1)*(acc+bias), in place
  {
    GArgs g = {};
    g.A[0] = midln_x; g.bias[0] = p1_b3; g.res[0] = h1x; g.C[0] = h1x; g.mcum[0] = 12; g.N[0] = 4096;
    g.A[1] = midln_c; g.bias[1] = p2_b3; g.res[1] = h1c; g.C[1] = h1c; g.mcum[1] = 16; g.N[1] = 4096;
    g.K = 1024; g.nd = 2;
    if (conv) {
      g.B[0] = b_w3p1; g.B[1] = b_w3p2;
      gemm_kernel<3, 0, 1, 1><<<dim3(32, 16), 256, 0, stream>>>(g, flag);
    } else {
      g.B[0] = p1_w3; g.B[1] = p2_w3;
      gemm_kernel<3, 0, 1, 0><<<dim3(32, 16), 256, 0, stream>>>(g, flag);
    }
  }
  // P5: W2 split-K=4. conv path: raw fp32 partials (no atomics, no zero) + reduce.
  //     fallback: zero + atomics as before.
  if (conv) {
    GArgs g = {};
    g.A[0] = h1x; g.bias[0] = p1_b2; g.res[0] = mid + (size_t)S * D; g.C[0] = d_out; g.oo[0] = 0;             g.mcum[0] = 12; g.N[0] = 1024;
    g.A[1] = h1c; g.bias[1] = p2_b2; g.res[1] = mid;                 g.C[1] = d_out; g.oo[1] = (size_t)L * D; g.mcum[1] = 16; g.N[1] = 1024;
    g.K = 4096; g.nd = 2;
    g.part = part;
    g.B[0] = b_w2p1; g.B[1] = b_w2p2;
    gemm_kernel<4, 3, 4, 1><<<dim3(8, 16, 4), 256, 0, stream>>>(g, flag);
    reduce_kernel<<<2048, 256, 0, stream>>>(part, mid, p1_b2, p2_b2, (float*)d_out, flag);
  } else {
    zero_kernel<<<2048, 256, 0, stream>>>(d_out, out_size, flag);
    GArgs g = {};
    g.A[0] = h1x; g.bias[0] = p1_b2; g.res[0] = mid + (size_t)S * D; g.C[0] = d_out; g.oo[0] = 0;             g.mcum[0] = 12; g.N[0] = 1024;
    g.A[1] = h1c; g.bias[1] = p2_b2; g.res[1] = mid;                 g.C[1] = d_out; g.oo[1] = (size_t)L * D; g.mcum[1] = 16; g.N[1] = 1024;
    g.K = 4096; g.nd = 2;
    g.B[0] = p1_w2; g.B[1] = p2_w2;
    gemm_kernel<4, 2, 4, 0><<<dim3(8, 16, 4), 256, 0, stream>>>(g, flag);
  }
}

// Round 7
// 500.556 us; speedup vs baseline: 1.0848x; 1.0225x over previous
//
#include <hip/hip_runtime.h>

typedef __attribute__((ext_vector_type(8))) short short8;
typedef __attribute__((ext_vector_type(4))) float floatx4;
typedef __attribute__((ext_vector_type(4))) unsigned short ushortx4;

// ---------- bf16 helpers ----------
__device__ __forceinline__ float bf2f(unsigned short u) {
  union { unsigned int i; float f; } v; v.i = ((unsigned int)u) << 16; return v.f;
}
__device__ __forceinline__ unsigned short f2bf(float f) {
  union { float f; unsigned int i; } v; v.f = f;
  unsigned int x = v.i + 0x7fffu + ((v.i >> 16) & 1u);
  return (unsigned short)(x >> 16);
}
__device__ __forceinline__ float loadE(const void* p, size_t i, int f) {
  return f ? ((const float*)p)[i] : bf2f(((const unsigned short*)p)[i]);
}
__device__ __forceinline__ uint4 packbf(float4 a, float4 b) {
  union { unsigned short u[8]; uint4 v; } p;
  p.u[0] = f2bf(a.x); p.u[1] = f2bf(a.y); p.u[2] = f2bf(a.z); p.u[3] = f2bf(a.w);
  p.u[4] = f2bf(b.x); p.u[5] = f2bf(b.y); p.u[6] = f2bf(b.z); p.u[7] = f2bf(b.w);
  return p.v;
}

// async global->LDS, 16B per lane. LDS dest = wave-uniform base + lane*16.
__device__ __forceinline__ void gl16(const unsigned short* g, unsigned short* l) {
  __builtin_amdgcn_global_load_lds(
      (const __attribute__((address_space(1))) void*)g,
      (__attribute__((address_space(3))) void*)l, 16, 0, 0);
}

// ---------- dtype detect ----------
__global__ void detect_kernel(const unsigned int* __restrict__ probe, int* __restrict__ flag) {
  if (threadIdx.x == 0 && blockIdx.x == 0) *flag = (probe[0] == 0x3F800000u) ? 1 : 0;
}

// ---------- one-shot weight conversion: all 12 weight matrices -> bf16 ----------
struct CArgs {
  const void* in[12];
  unsigned short* out[12];
  unsigned int cum[12];  // cumulative chunk (8-elem) counts
};
__global__ __launch_bounds__(256) void convw_kernel(CArgs a, int total_chunks,
                                                    const int* __restrict__ flagp) {
  const int flag = *flagp;
  for (int c = blockIdx.x * 256 + threadIdx.x; c < total_chunks; c += gridDim.x * 256) {
    int s = 0;
    while (c >= (int)a.cum[s]) ++s;
    unsigned int base = s ? a.cum[s - 1] : 0u;
    size_t e = (size_t)(c - base) * 8;
    if (flag) {
      const float* in = (const float*)a.in[s] + e;
      float4 v0 = *(const float4*)in;
      float4 v1 = *(const float4*)(in + 4);
      *(uint4*)(a.out[s] + e) = packbf(v0, v1);
    } else {
      *(uint4*)(a.out[s] + e) = *(const uint4*)((const unsigned short*)a.in[s] + e);
    }
  }
}

// ---------- zero d_out (fallback path only) ----------
__global__ __launch_bounds__(256) void zero_kernel(void* __restrict__ out, int out_elems,
                                                   const int* __restrict__ flagp) {
  int limit = (*flagp) ? (out_elems >> 2) : (out_elems >> 3);  // uint4 chunks
  int i = blockIdx.x * 256 + threadIdx.x;
  if (i < limit) ((uint4*)out)[i] = make_uint4(0, 0, 0, 0);
}

// ---------- split-K partial reduce: d_out = sum_z part[z] + bias + res(mid) ----------
__global__ __launch_bounds__(256) void reduce_kernel(const float* __restrict__ part,
                                                     const unsigned short* __restrict__ mid,
                                                     const void* __restrict__ b1,   // p1_b2 (x rows)
                                                     const void* __restrict__ b2,   // p2_b2 (c rows)
                                                     float* __restrict__ out,
                                                     const int* __restrict__ flagp) {
  if (!*flagp) return;
  const size_t TD = 2097152, LD = (size_t)1536 * 1024, SD = (size_t)512 * 1024;
  size_t i = ((size_t)blockIdx.x * 256 + threadIdx.x) * 4;
  if (i >= TD) return;
  float4 v  = *(const float4*)(part + i);
  float4 v1 = *(const float4*)(part + TD + i);
  float4 v2 = *(const float4*)(part + 2 * TD + i);
  float4 v3 = *(const float4*)(part + 3 * TD + i);
  v.x += v1.x + v2.x + v3.x;
  v.y += v1.y + v2.y + v3.y;
  v.z += v1.z + v2.z + v3.z;
  v.w += v1.w + v2.w + v3.w;
  int col = (int)(i & 1023);
  const float* bias = (const float*)((i < LD) ? b1 : b2);
  size_t ri = (i < LD) ? (SD + i) : (i - LD);
  v.x += bias[col + 0] + bf2f(mid[ri + 0]);
  v.y += bias[col + 1] + bf2f(mid[ri + 1]);
  v.z += bias[col + 2] + bf2f(mid[ri + 2]);
  v.w += bias[col + 3] + bf2f(mid[ri + 3]);
  *(float4*)(out + i) = v;
}

// ---------- LayerNorm over both external inputs -> unified bf16 (c rows first) ----------
__global__ __launch_bounds__(256) void ln_ext_kernel(const void* __restrict__ cin,
                                                     const void* __restrict__ xin,
                                                     unsigned short* __restrict__ out,
                                                     const int* __restrict__ flagp) {
  const int D = 1024, S = 512;
  const int flag = *flagp;
  int row = blockIdx.x;
  const void* src = (row < S) ? cin : xin;
  size_t rb = (size_t)(row < S ? row : row - S) * D;
  int base = threadIdx.x * 4;
  float x0 = loadE(src, rb + base + 0, flag);
  float x1 = loadE(src, rb + base + 1, flag);
  float x2 = loadE(src, rb + base + 2, flag);
  float x3 = loadE(src, rb + base + 3, flag);
  float s1 = x0 + x1 + x2 + x3;
  float s2 = x0 * x0 + x1 * x1 + x2 * x2 + x3 * x3;
  for (int off = 32; off; off >>= 1) {
    s1 += __shfl_down(s1, off, 64);
    s2 += __shfl_down(s2, off, 64);
  }
  __shared__ float red[8];
  int wid = threadIdx.x >> 6;
  if ((threadIdx.x & 63) == 0) { red[wid] = s1; red[4 + wid] = s2; }
  __syncthreads();
  s1 = red[0] + red[1] + red[2] + red[3];
  s2 = red[4] + red[5] + red[6] + red[7];
  float mean = s1 * (1.0f / D);
  float var = s2 * (1.0f / D) - mean * mean;
  float inv = rsqrtf(var + 1e-6f);
  unsigned short* dst = out + (size_t)row * D + base;
  dst[0] = f2bf((x0 - mean) * inv);
  dst[1] = f2bf((x1 - mean) * inv);
  dst[2] = f2bf((x2 - mean) * inv);
  dst[3] = f2bf((x3 - mean) * inv);
}

// ---------- LayerNorm over internal bf16 mid; split outputs ----------
__global__ __launch_bounds__(256) void ln_mid_kernel(const unsigned short* __restrict__ in,
                                                     unsigned short* __restrict__ outc,
                                                     unsigned short* __restrict__ outx) {
  const int D = 1024, S = 512;
  int row = blockIdx.x;
  const unsigned short* src = in + (size_t)row * D;
  int base = threadIdx.x * 4;
  float x0 = bf2f(src[base + 0]);
  float x1 = bf2f(src[base + 1]);
  float x2 = bf2f(src[base + 2]);
  float x3 = bf2f(src[base + 3]);
  float s1 = x0 + x1 + x2 + x3;
  float s2 = x0 * x0 + x1 * x1 + x2 * x2 + x3 * x3;
  for (int off = 32; off; off >>= 1) {
    s1 += __shfl_down(s1, off, 64);
    s2 += __shfl_down(s2, off, 64);
  }
  __shared__ float red[8];
  int wid = threadIdx.x >> 6;
  if ((threadIdx.x & 63) == 0) { red[wid] = s1; red[4 + wid] = s2; }
  __syncthreads();
  s1 = red[0] + red[1] + red[2] + red[3];
  s2 = red[4] + red[5] + red[6] + red[7];
  float mean = s1 * (1.0f / D);
  float var = s2 * (1.0f / D) - mean * mean;
  float inv = rsqrtf(var + 1e-6f);
  unsigned short* dst = (row < S ? outc + (size_t)row * D : outx + (size_t)(row - S) * D) + base;
  dst[0] = f2bf((x0 - mean) * inv);
  dst[1] = f2bf((x1 - mean) * inv);
  dst[2] = f2bf((x2 - mean) * inv);
  dst[3] = f2bf((x3 - mean) * inv);
}

// ---------- multi-descriptor GEMM (round-6 structure, unchanged except tmask) ----------
// tmask bit d: OUT_MODE 0 store TRANSPOSED bf16 at C[col*2048 + oo + row] (V^T for attn;
// per-lane rows are contiguous -> one ushort4 store).
struct GArgs {
  const unsigned short* A[4];
  const void* B[4];
  const void* bias[4];
  const void* res[4];
  void* C[4];
  unsigned long long oo[4];
  int mcum[4];  // cumulative m-tile counts
  int N[4];
  int K;
  int nd;
  int tmask;
  float* part;  // split-K partial base (OUT_MODE 3), slice stride 2048*1024
};

#define BAR() asm volatile("s_waitcnt lgkmcnt(0)\n\ts_barrier" ::: "memory")
#define FBAR() asm volatile("s_waitcnt vmcnt(0) lgkmcnt(0)\n\ts_barrier" ::: "memory")

template <int RES_MODE, int OUT_MODE, int SPLITK, int BBF16>
__global__ __launch_bounds__(256) void gemm_kernel(GArgs g, const int* __restrict__ flagp) {
  const int flag = *flagp;
  int by = blockIdx.y;
  int d = 0;
  while (d < g.nd - 1 && by >= g.mcum[d]) ++d;
  int mbase = (d == 0) ? 0 : g.mcum[d - 1];
  const int m0 = (by - mbase) * 128;
  const int N = g.N[d];
  const int n0 = blockIdx.x * 128;
  if (n0 >= N) return;  // block-uniform
  const int K = g.K;
  int kbeg = 0, kend = K;
  if (SPLITK > 1) {
    if (!flag) {
      if (blockIdx.z != 0) return;
    } else {
      int kl = K / SPLITK;
      kbeg = blockIdx.z * kl;
      kend = kbeg + kl;
    }
  }
  const int nt = (kend - kbeg) >> 5;

  constexpr int BSTRIDE = BBF16 ? 4096 : 5120;
  __shared__ __align__(16) unsigned short sA[2 * BSTRIDE];
  __shared__ __align__(16) unsigned short sB[2 * BSTRIDE];

  const int tid = threadIdx.x;
  const int lane = tid & 63;
  const int wave = tid >> 6;
  const int wm = (wave >> 1) * 64, wn = (wave & 1) * 64;
  const int srow = tid >> 2;
  const int scol = BBF16 ? ((((tid & 3) ^ ((tid >> 3) & 3))) * 8) : ((tid & 3) * 8);
  const unsigned short* Ag0 = g.A[d] + (size_t)(m0 + srow) * K + kbeg + scol;
  const unsigned short* Ag1 = Ag0 + (size_t)64 * K;
  const unsigned short* Bh0 = (const unsigned short*)g.B[d] + (size_t)(n0 + srow) * K + kbeg + scol;
  const unsigned short* Bh1 = Bh0 + (size_t)64 * K;

  const int fr = lane & 15;
  const int rdo = BBF16 ? ((((lane >> 4) ^ ((fr >> 1) & 3))) * 8) : ((lane >> 4) * 8);
  constexpr int PITCH = BBF16 ? 32 : 40;
  floatx4 acc[4][4] = {};
  auto compute = [&](const unsigned short* as, const unsigned short* bs) {
    short8 af[4], bfr[4];
    #pragma unroll
    for (int i = 0; i < 4; ++i) {
      af[i]  = *(const short8*)(as + (wm + i * 16 + fr) * PITCH + rdo);
      bfr[i] = *(const short8*)(bs + (wn + i * 16 + fr) * PITCH + rdo);
    }
    #pragma unroll
    for (int mi = 0; mi < 4; ++mi)
      #pragma unroll
      for (int ni = 0; ni < 4; ++ni)
        acc[mi][ni] = __builtin_amdgcn_mfma_f32_16x16x32_bf16(af[mi], bfr[ni], acc[mi][ni], 0, 0, 0);
  };

  if (BBF16) {
    unsigned short* lA0 = sA + wave * 512;
    unsigned short* lA1 = lA0 + 2048;
    unsigned short* lB0 = sB + wave * 512;
    unsigned short* lB1 = lB0 + 2048;
    auto stage = [&](int buf, int kk) {
      int bo = buf * 4096;
      gl16(Ag0 + kk, lA0 + bo);
      gl16(Ag1 + kk, lA1 + bo);
      gl16(Bh0 + kk, lB0 + bo);
      gl16(Bh1 + kk, lB1 + bo);
    };
    stage(0, 0);
    FBAR();
    for (int t = 0; t < nt; ++t) {
      if (t + 1 < nt) stage((t + 1) & 1, (t + 1) * 32);
      compute(sA + (t & 1) * 4096, sB + (t & 1) * 4096);
      if (t + 1 < nt) FBAR();
    }
  } else {
    const float* Bf0 = (const float*)g.B[d] + (size_t)(n0 + srow) * K + kbeg + scol;
    const float* Bf1 = Bf0 + (size_t)64 * K;
    const int wo0 = srow * 40 + scol;
    const int wo1 = wo0 + 64 * 40;
    uint4 ra0, ra1, rb0, rb1;
    auto load_tile = [&](int kk) {
      ra0 = *(const uint4*)(Ag0 + kk);
      ra1 = *(const uint4*)(Ag1 + kk);
      if (!flag) {
        rb0 = *(const uint4*)(Bh0 + kk);
        rb1 = *(const uint4*)(Bh1 + kk);
      } else {
        float4 x0 = *(const float4*)(Bf0 + kk), x1 = *(const float4*)(Bf0 + kk + 4);
        float4 y0 = *(const float4*)(Bf1 + kk), y1 = *(const float4*)(Bf1 + kk + 4);
        rb0 = packbf(x0, x1);
        rb1 = packbf(y0, y1);
      }
    };
    auto store_tile = [&](int buf) {
      unsigned short* sa = sA + buf * 5120;
      unsigned short* sb = sB + buf * 5120;
      *(uint4*)(sa + wo0) = ra0;
      *(uint4*)(sa + wo1) = ra1;
      *(uint4*)(sb + wo0) = rb0;
      *(uint4*)(sb + wo1) = rb1;
    };
    load_tile(0);
    store_tile(0);
    if (nt > 1) load_tile(32);
    BAR();
    for (int t = 0; t < nt; ++t) {
      if (t + 1 < nt) {
        store_tile((t + 1) & 1);
        if (t + 2 < nt) load_tile((t + 2) * 32);
      }
      compute(sA + (t & 1) * 5120, sB + (t & 1) * 5120);
      if (t + 1 < nt) BAR();
    }
  }

  const void* bias = g.bias[d];
  const void* res = g.res[d];
  void* C = g.C[d];
  const size_t oo = g.oo[d];
  const bool first = (SPLITK <= 1) || (blockIdx.z == 0) || !flag;
  const bool rawpart = (OUT_MODE == 3) && (flag != 0);
  const bool trans = (OUT_MODE == 0) && (((g.tmask) >> d) & 1);
  #pragma unroll
  for (int mi = 0; mi < 4; ++mi)
    #pragma unroll
    for (int ni = 0; ni < 4; ++ni) {
      int colb = n0 + wn + ni * 16 + (lane & 15);
      int rowb = m0 + wm + mi * 16 + (lane >> 4) * 4;
      if (trans) {
        // transposed bf16 store: rows contiguous per lane -> one 8B store
        ushortx4 o4;
        #pragma unroll
        for (int r = 0; r < 4; ++r) {
          float val = acc[mi][ni][r];
          if (bias) val += loadE(bias, (size_t)colb, flag);
          o4[r] = f2bf(val);
        }
        *(ushortx4*)((unsigned short*)C + (size_t)colb * 2048 + oo + rowb) = o4;
      } else {
        #pragma unroll
        for (int r = 0; r < 4; ++r) {
          int row = rowb + r;
          int col = colb;
          float val = acc[mi][ni][r];
          size_t off = (size_t)row * N + col;
          if (first && !rawpart) {
            if (bias) val += loadE(bias, (size_t)col, flag);
            if (RES_MODE == 1) val += loadE(res, off, flag);
            if (RES_MODE == 3) {
              float h1v = bf2f(((const unsigned short*)res)[off]);
              val = (h1v / (1.0f + __expf(-h1v))) * val;
            }
            if (RES_MODE == 4) val += bf2f(((const unsigned short*)res)[off]);
          }
          if (OUT_MODE == 0) {
            ((unsigned short*)C)[off] = f2bf(val);
          } else if (OUT_MODE == 3) {
            if (flag) g.part[(size_t)blockIdx.z * 2097152 + oo + off] = val;
            else      ((unsigned short*)C)[oo + off] = f2bf(val);
          } else {  // OUT_MODE == 2 (fallback)
            if (flag) {
              if (SPLITK > 1) atomicAdd((float*)C + oo + off, val);
              else            ((float*)C)[oo + off] = val;
            } else {
              ((unsigned short*)C)[oo + off] = f2bf(val);
            }
          }
        }
      }
    }
}

// ---------- per-(t,head) RMSNorm + RoPE, 4 heads/block, in place ----------
__global__ __launch_bounds__(256) void rmsrope_kernel(
    unsigned short* __restrict__ qk,
    const void* __restrict__ qn_c, const void* __restrict__ kn_c,
    const void* __restrict__ qn_x, const void* __restrict__ kn_x,
    const void* __restrict__ freqs, const int* __restrict__ flagp) {
  const int flag = *flagp;
  int t = blockIdx.x;
  int h = blockIdx.y * 4 + (threadIdx.x >> 6);
  int d = threadIdx.x & 63;
  unsigned short* qrow = qk + (size_t)t * 2048 + h * 64;
  unsigned short* krow = qrow + 1024;
  float q = bf2f(qrow[d]), k = bf2f(krow[d]);
  float qs = q * q, ks = k * k;
  for (int off = 32; off; off >>= 1) {
    qs += __shfl_xor(qs, off, 64);
    ks += __shfl_xor(ks, off, 64);
  }
  const void* qn = (t < 512) ? qn_c : qn_x;
  const void* kn = (t < 512) ? kn_c : kn_x;
  q = q * rsqrtf(qs * (1.0f / 64.0f) + 1e-6f) * loadE(qn, d, flag);
  k = k * rsqrtf(ks * (1.0f / 64.0f) + 1e-6f) * loadE(kn, d, flag);
  int j = d >> 1;
  float cv = loadE(freqs, (size_t)(t * 32 + j) * 2 + 0, flag);
  float sv = loadE(freqs, (size_t)(t * 32 + j) * 2 + 1, flag);
  float qo = __shfl_xor(q, 1, 64);
  float ko = __shfl_xor(k, 1, 64);
  float qn2, kn2;
  if ((d & 1) == 0) { qn2 = q * cv - qo * sv; kn2 = k * cv - ko * sv; }
  else              { qn2 = qo * sv + q * cv; kn2 = ko * sv + k * cv; }
  qrow[d] = f2bf(qn2);
  krow[d] = f2bf(kn2);
}

// ---------- MFMA flash attention, round-7 staging ----------
// 64 Q-rows/block (4 waves x 16), 64-key tiles. K and V^T tiles staged via
// global_load_lds into linear [64][64] LDS with XOR-chunk swizzle (chunk^=row&7,
// both-sides involution: pre-swizzled global source + swizzled ds_read).
// Double-buffered: stage tile t+1 before computing tile t; ONE vmcnt+barrier per
// tile (load latency hides under QK+softmax+PV). V arrives pre-transposed from P1
// (tmask store) -> the old 16-scalar-ds_write transpose is gone.
__global__ __launch_bounds__(256) void attn_kernel(const unsigned short* __restrict__ qk,
                                                   const unsigned short* __restrict__ vT,
                                                   unsigned short* __restrict__ y) {
  int id = blockIdx.x;
  int blk = (id & 256) ? (31 - (id & 31)) : (id & 31);
  int h = (id >> 5) & 15;
  int wv = threadIdx.x >> 6;
  int lane = threadIdx.x & 63;
  int qbase = blk * 64 + wv * 16;

  __shared__ __align__(16) unsigned short Ks[2 * 4096];  // [buf][key][64 d] swz
  __shared__ __align__(16) unsigned short Vs[2 * 4096];  // [buf][d][64 key] swz
  __shared__ __align__(16) unsigned short ps[4][16 * 72];

  // staging geometry: chunk c in {wv*64+lane, 256+wv*64+lane}; row=c>>3, k=c&7,
  // physical chunk k holds global chunk k^(row&7) (source pre-swizzle).
  const int c0 = wv * 64 + lane;
  const int r0 = c0 >> 3,         k0 = (c0 & 7) ^ (r0 & 7);
  const int r1 = (c0 + 256) >> 3, k1 = (c0 & 7) ^ (r1 & 7);
  unsigned short* kd0 = Ks + wv * 512;
  unsigned short* kd1 = Ks + 2048 + wv * 512;
  unsigned short* vd0 = Vs + wv * 512;
  unsigned short* vd1 = Vs + 2048 + wv * 512;
  const unsigned short* kgp0 = qk + 1024 + h * 64 + k0 * 8 + (size_t)r0 * 2048;
  const unsigned short* kgp1 = qk + 1024 + h * 64 + k1 * 8 + (size_t)r1 * 2048;
  const unsigned short* vgp0 = vT + (size_t)(h * 64 + r0) * 2048 + k0 * 8;
  const unsigned short* vgp1 = vT + (size_t)(h * 64 + r1) * 2048 + k1 * 8;
  auto stage = [&](int buf, int j0) {
    int bo = buf * 4096;
    gl16(kgp0 + (size_t)j0 * 2048, kd0 + bo);
    gl16(kgp1 + (size_t)j0 * 2048, kd1 + bo);
    gl16(vgp0 + j0, vd0 + bo);
    gl16(vgp1 + j0, vd1 + bo);
  };

  short8 qa[2];
  {
    int m = lane & 15, dj = (lane >> 4) * 8;
    const unsigned short* qp = qk + (size_t)(qbase + m) * 2048 + h * 64 + dj;
    qa[0] = *(const short8*)(qp);
    qa[1] = *(const short8*)(qp + 32);
  }
  floatx4 o[4] = {};
  float mrow[4] = {-1e30f, -1e30f, -1e30f, -1e30f};
  float lrow[4] = {0.f, 0.f, 0.f, 0.f};
  int ntiles = blk + 1;

  stage(0, 0);
  FBAR();
  for (int tile = 0; tile < ntiles; ++tile) {
    int j0 = tile * 64;
    if (tile + 1 < ntiles) stage((tile + 1) & 1, j0 + 64);
    const unsigned short* Kb = Ks + (tile & 1) * 4096;
    const unsigned short* Vb = Vs + (tile & 1) * 4096;
    floatx4 sacc[4];
    #pragma unroll
    for (int kg = 0; kg < 4; ++kg) {
      floatx4 z = {0.f, 0.f, 0.f, 0.f};
      #pragma unroll
      for (int kc = 0; kc < 2; ++kc) {
        int kr = kg * 16 + (lane & 15);
        int p = (kc * 4 + (lane >> 4)) ^ (kr & 7);
        short8 kb = *(const short8*)(Kb + kr * 64 + p * 8);
        z = __builtin_amdgcn_mfma_f32_16x16x32_bf16(qa[kc], kb, z, 0, 0, 0);
      }
      sacc[kg] = z;
    }
    #pragma unroll
    for (int kg = 0; kg < 4; ++kg)
      #pragma unroll
      for (int r = 0; r < 4; ++r) {
        int key_g = j0 + kg * 16 + (lane & 15);
        int q_g = qbase + (lane >> 4) * 4 + r;
        float s = sacc[kg][r] * 0.125f;
        sacc[kg][r] = (key_g <= q_g) ? s : -1e30f;
      }
    #pragma unroll
    for (int r = 0; r < 4; ++r) {
      float mx = fmaxf(fmaxf(sacc[0][r], sacc[1][r]), fmaxf(sacc[2][r], sacc[3][r]));
      mx = fmaxf(mx, __shfl_xor(mx, 1, 64));
      mx = fmaxf(mx, __shfl_xor(mx, 2, 64));
      mx = fmaxf(mx, __shfl_xor(mx, 4, 64));
      mx = fmaxf(mx, __shfl_xor(mx, 8, 64));
      float mnew = fmaxf(mrow[r], mx);
      float al = __expf(mrow[r] - mnew);
      mrow[r] = mnew;
      float sum = 0.f;
      #pragma unroll
      for (int kg = 0; kg < 4; ++kg) {
        float p = __expf(sacc[kg][r] - mnew);
        sacc[kg][r] = p;
        sum += p;
      }
      sum += __shfl_xor(sum, 1, 64);
      sum += __shfl_xor(sum, 2, 64);
      sum += __shfl_xor(sum, 4, 64);
      sum += __shfl_xor(sum, 8, 64);
      lrow[r] = lrow[r] * al + sum;
      #pragma unroll
      for (int ni = 0; ni < 4; ++ni) o[ni][r] *= al;
    }
    unsigned short* pw = ps[wv];
    #pragma unroll
    for (int kg = 0; kg < 4; ++kg)
      #pragma unroll
      for (int r = 0; r < 4; ++r)
        pw[((lane >> 4) * 4 + r) * 72 + kg * 16 + (lane & 15)] = f2bf(sacc[kg][r]);
    asm volatile("s_waitcnt lgkmcnt(0)" ::: "memory");
    short8 pa[2];
    pa[0] = *(const short8*)(pw + (lane & 15) * 72 + (lane >> 4) * 8);
    pa[1] = *(const short8*)(pw + (lane & 15) * 72 + 32 + (lane >> 4) * 8);
    #pragma unroll
    for (int ni = 0; ni < 4; ++ni) {
      floatx4 z = o[ni];
      int dd = ni * 16 + (lane & 15);
      #pragma unroll
      for (int kc = 0; kc < 2; ++kc) {
        int p = (kc * 4 + (lane >> 4)) ^ (dd & 7);
        short8 vb = *(const short8*)(Vb + dd * 64 + p * 8);
        z = __builtin_amdgcn_mfma_f32_16x16x32_bf16(pa[kc], vb, z, 0, 0, 0);
      }
      o[ni] = z;
    }
    if (tile + 1 < ntiles) FBAR();
  }
  #pragma unroll
  for (int ni = 0; ni < 4; ++ni)
    #pragma unroll
    for (int r = 0; r < 4; ++r) {
      int q = qbase + (lane >> 4) * 4 + r;
      int dd = ni * 16 + (lane & 15);
      y[(size_t)q * 1024 + h * 64 + dd] = f2bf(o[ni][r] / lrow[r]);
    }
}

extern "C" void kernel_launch(void* const* d_in, const int* in_sizes, int n_in,
                              void* d_out, int out_size, void* d_ws, size_t ws_size,
                              hipStream_t stream) {
  const int L = 1536, S = 512, D = 1024, T = 2048, FF = 4096;
  const void* x        = d_in[0];
  const void* c        = d_in[1];
  const void* freqs    = d_in[2];
  const void* px_qk_w  = d_in[3];
  const void* px_qn    = d_in[4];
  const void* px_kn    = d_in[5];
  const void* px_v_w   = d_in[6];
  const void* px_v_b   = d_in[7];
  const void* pc_qk_w  = d_in[8];
  const void* pc_qn    = d_in[9];
  const void* pc_kn    = d_in[10];
  const void* pc_v_w   = d_in[11];
  const void* pc_v_b   = d_in[12];
  const void* p1_proj_w = d_in[13];
  const void* p1_proj_b = d_in[14];
  const void* p1_w1 = d_in[15];
  const void* p1_b1 = d_in[16];
  const void* p1_w3 = d_in[17];
  const void* p1_b3 = d_in[18];
  const void* p1_w2 = d_in[19];
  const void* p1_b2 = d_in[20];
  const void* p2_proj_w = d_in[21];
  const void* p2_proj_b = d_in[22];
  const void* p2_w1 = d_in[23];
  const void* p2_b1 = d_in[24];
  const void* p2_w3 = d_in[25];
  const void* p2_b3 = d_in[26];
  const void* p2_w2 = d_in[27];
  const void* p2_b2 = d_in[28];

  // Workspace layout: see round-6 comments. vbuf region now holds V^T [1024][2048].
  char* ws = (char*)d_ws;
  unsigned short* hln     = (unsigned short*)(ws);
  unsigned short* ybuf    = (unsigned short*)(ws);
  unsigned short* h1c     = (unsigned short*)(ws);
  unsigned short* qkbuf   = (unsigned short*)(ws + ((size_t)4  << 20));
  unsigned short* h1x     = (unsigned short*)(ws + ((size_t)4  << 20));
  unsigned short* vbufT   = (unsigned short*)(ws + ((size_t)12 << 20));
  unsigned short* mid     = (unsigned short*)(ws + ((size_t)16 << 20));
  unsigned short* midln_c = (unsigned short*)(ws + ((size_t)20 << 20));
  int*            flag    = (int*)(ws + ((size_t)21 << 20));
  unsigned short* midln_x = (unsigned short*)d_out;
  unsigned short* hlnx    = hln + (size_t)S * D;

  const bool conv = ws_size >= ((size_t)90 << 20);
  unsigned short* wbf = (unsigned short*)(ws + ((size_t)24 << 20));
  unsigned short* b_qk_c = wbf + 0;
  unsigned short* b_qk_x = wbf + 2097152;
  unsigned short* b_v_c  = wbf + 4194304;
  unsigned short* b_v_x  = wbf + 5242880;
  unsigned short* b_pj1  = wbf + 6291456;
  unsigned short* b_pj2  = wbf + 7340032;
  unsigned short* b_w1p1 = wbf + 8388608;
  unsigned short* b_w1p2 = wbf + 12582912;
  unsigned short* b_w3p1 = wbf + 16777216;
  unsigned short* b_w3p2 = wbf + 20971520;
  unsigned short* b_w2p1 = wbf + 25165824;
  unsigned short* b_w2p2 = wbf + 29360128;
  float* part = (float*)(ws + ((size_t)40 << 20));

  detect_kernel<<<1, 64, 0, stream>>>((const unsigned int*)px_qn, flag);

  if (conv) {
    CArgs ca;
    const void* ins[12]   = {pc_qk_w, px_qk_w, pc_v_w, px_v_w, p1_proj_w, p2_proj_w,
                             p1_w1, p2_w1, p1_w3, p2_w3, p1_w2, p2_w2};
    unsigned short* os[12] = {b_qk_c, b_qk_x, b_v_c, b_v_x, b_pj1, b_pj2,
                              b_w1p1, b_w1p2, b_w3p1, b_w3p2, b_w2p1, b_w2p2};
    unsigned int cnt[12]  = {262144, 262144, 131072, 131072, 131072, 131072,
                             524288, 524288, 524288, 524288, 524288, 524288};
    unsigned int cum = 0;
    for (int i = 0; i < 12; ++i) { ca.in[i] = ins[i]; ca.out[i] = os[i]; cum += cnt[i]; ca.cum[i] = cum; }
    convw_kernel<<<2048, 256, 0, stream>>>(ca, (int)cum, flag);
  }

  ln_ext_kernel<<<T, 256, 0, stream>>>(c, x, hln, flag);

  // P1: QKV (4 descriptors). V descs (2,3) store TRANSPOSED into vbufT (tmask).
  {
    GArgs g = {};
    g.A[0] = hln;  g.bias[0] = nullptr; g.C[0] = qkbuf;                    g.mcum[0] = 4;  g.N[0] = 2048;
    g.A[1] = hlnx; g.bias[1] = nullptr; g.C[1] = qkbuf + (size_t)S * 2048; g.mcum[1] = 16; g.N[1] = 2048;
    g.A[2] = hln;  g.bias[2] = pc_v_b;  g.C[2] = vbufT; g.oo[2] = 0;       g.mcum[2] = 20; g.N[2] = 1024;
    g.A[3] = hlnx; g.bias[3] = px_v_b;  g.C[3] = vbufT; g.oo[3] = S;       g.mcum[3] = 32; g.N[3] = 1024;
    g.K = 1024; g.nd = 4; g.tmask = 0b1100;
    if (conv) {
      g.B[0] = b_qk_c; g.B[1] = b_qk_x; g.B[2] = b_v_c; g.B[3] = b_v_x;
      gemm_kernel<0, 0, 1, 1><<<dim3(16, 32), 256, 0, stream>>>(g, flag);
    } else {
      g.B[0] = pc_qk_w; g.B[1] = px_qk_w; g.B[2] = pc_v_w; g.B[3] = px_v_w;
      gemm_kernel<0, 0, 1, 0><<<dim3(16, 32), 256, 0, stream>>>(g, flag);
    }
  }
  rmsrope_kernel<<<dim3(T, 4), 256, 0, stream>>>(qkbuf, pc_qn, pc_kn, px_qn, px_kn, freqs, flag);
  attn_kernel<<<512, 256, 0, stream>>>(qkbuf, vbufT, ybuf);

  // P2: out-projection + external residual -> mid
  {
    GArgs g = {};
    g.A[0] = ybuf;                  g.bias[0] = p2_proj_b; g.res[0] = c; g.C[0] = mid;                  g.mcum[0] = 4;  g.N[0] = 1024;
    g.A[1] = ybuf + (size_t)S * D;  g.bias[1] = p1_proj_b; g.res[1] = x; g.C[1] = mid + (size_t)S * D;  g.mcum[1] = 16; g.N[1] = 1024;
    g.K = 1024; g.nd = 2;
    if (conv) {
      g.B[0] = b_pj2; g.B[1] = b_pj1;
      gemm_kernel<1, 0, 1, 1><<<dim3(8, 16), 256, 0, stream>>>(g, flag);
    } else {
      g.B[0] = p2_proj_w; g.B[1] = p1_proj_w;
      gemm_kernel<1, 0, 1, 0><<<dim3(8, 16), 256, 0, stream>>>(g, flag);
    }
  }
  ln_mid_kernel<<<T, 256, 0, stream>>>(mid, midln_c, midln_x);

  // P3: W1 (x + c merged)
  {
    GArgs g = {};
    g.A[0] = midln_x; g.bias[0] = p1_b1; g.C[0] = h1x; g.mcum[0] = 12; g.N[0] = 4096;
    g.A[1] = midln_c; g.bias[1] = p2_b1; g.C[1] = h1c; g.mcum[1] = 16; g.N[1] = 4096;
    g.K = 1024; g.nd = 2;
    if (conv) {
      g.B[0] = b_w1p1; g.B[1] = b_w1p2;
      gemm_kernel<0, 0, 1, 1><<<dim3(32, 16), 256, 0, stream>>>(g, flag);
    } else {
      g.B[0] = p1_w1; g.B[1] = p2_w1;
      gemm_kernel<0, 0, 1, 0><<<dim3(32, 16), 256, 0, stream>>>(g, flag);
    }
  }
  // P4: W3 with fused silu(h1)*(acc+bias), in place
  {
    GArgs g = {};
    g.A[0] = midln_x; g.bias[0] = p1_b3; g.res[0] = h1x; g.C[0] = h1x; g.mcum[0] = 12; g.N[0] = 4096;
    g.A[1] = midln_c; g.bias[1] = p2_b3; g.res[1] = h1c; g.C[1] = h1c; g.mcum[1] = 16; g.N[1] = 4096;
    g.K = 1024; g.nd = 2;
    if (conv) {
      g.B[0] = b_w3p1; g.B[1] = b_w3p2;
      gemm_kernel<3, 0, 1, 1><<<dim3(32, 16), 256, 0, stream>>>(g, flag);
    } else {
      g.B[0] = p1_w3; g.B[1] = p2_w3;
      gemm_kernel<3, 0, 1, 0><<<dim3(32, 16), 256, 0, stream>>>(g, flag);
    }
  }
  // P5: W2 split-K=4. conv: raw fp32 partials + reduce. fallback: zero + atomics.
  if (conv) {
    GArgs g = {};
    g.A[0] = h1x; g.bias[0] = p1_b2; g.res[0] = mid + (size_t)S * D; g.C[0] = d_out; g.oo[0] = 0;             g.mcum[0] = 12; g.N[0] = 1024;
    g.A[1] = h1c; g.bias[1] = p2_b2; g.res[1] = mid;                 g.C[1] = d_out; g.oo[1] = (size_t)L * D; g.mcum[1] = 16; g.N[1] = 1024;
    g.K = 4096; g.nd = 2;
    g.part = part;
    g.B[0] = b_w2p1; g.B[1] = b_w2p2;
    gemm_kernel<4, 3, 4, 1><<<dim3(8, 16, 4), 256, 0, stream>>>(g, flag);
    reduce_kernel<<<2048, 256, 0, stream>>>(part, mid, p1_b2, p2_b2, (float*)d_out, flag);
  } else {
    zero_kernel<<<2048, 256, 0, stream>>>(d_out, out_size, flag);
    GArgs g = {};
    g.A[0] = h1x; g.bias[0] = p1_b2; g.res[0] = mid + (size_t)S * D; g.C[0] = d_out; g.oo[0] = 0;             g.mcum[0] = 12; g.N[0] = 1024;
    g.A[1] = h1c; g.bias[1] = p2_b2; g.res[1] = mid;                 g.C[1] = d_out; g.oo[1] = (size_t)L * D; g.mcum[1] = 16; g.N[1] = 1024;
    g.K = 4096; g.nd = 2;
    g.B[0] = p1_w2; g.B[1] = p2_w2;
    gemm_kernel<4, 2, 4, 0><<<dim3(8, 16, 4), 256, 0, stream>>>(g, flag);
  }
}

// Round 9
// 495.613 us; speedup vs baseline: 1.0956x; 1.0100x over previous
//
#include <hip/hip_runtime.h>

typedef __attribute__((ext_vector_type(8))) short short8;
typedef __attribute__((ext_vector_type(4))) float floatx4;
typedef __attribute__((ext_vector_type(4))) unsigned short ushortx4;

// ---------- bf16 helpers ----------
__device__ __forceinline__ float bf2f(unsigned short u) {
  union { unsigned int i; float f; } v; v.i = ((unsigned int)u) << 16; return v.f;
}
__device__ __forceinline__ unsigned short f2bf(float f) {
  union { float f; unsigned int i; } v; v.f = f;
  unsigned int x = v.i + 0x7fffu + ((v.i >> 16) & 1u);
  return (unsigned short)(x >> 16);
}
__device__ __forceinline__ float loadE(const void* p, size_t i, int f) {
  return f ? ((const float*)p)[i] : bf2f(((const unsigned short*)p)[i]);
}
__device__ __forceinline__ uint4 packbf(float4 a, float4 b) {
  union { unsigned short u[8]; uint4 v; } p;
  p.u[0] = f2bf(a.x); p.u[1] = f2bf(a.y); p.u[2] = f2bf(a.z); p.u[3] = f2bf(a.w);
  p.u[4] = f2bf(b.x); p.u[5] = f2bf(b.y); p.u[6] = f2bf(b.z); p.u[7] = f2bf(b.w);
  return p.v;
}

// async global->LDS, 16B per lane. LDS dest = wave-uniform base + lane*16.
__device__ __forceinline__ void gl16(const unsigned short* g, unsigned short* l) {
  __builtin_amdgcn_global_load_lds(
      (const __attribute__((address_space(1))) void*)g,
      (__attribute__((address_space(3))) void*)l, 16, 0, 0);
}

// ---------- dtype detect ----------
__global__ void detect_kernel(const unsigned int* __restrict__ probe, int* __restrict__ flag) {
  if (threadIdx.x == 0 && blockIdx.x == 0) *flag = (probe[0] == 0x3F800000u) ? 1 : 0;
}

// ---------- one-shot weight conversion: all 12 weight matrices -> bf16 ----------
struct CArgs {
  const void* in[12];
  unsigned short* out[12];
  unsigned int cum[12];  // cumulative chunk (8-elem) counts
};
__global__ __launch_bounds__(256) void convw_kernel(CArgs a, int total_chunks,
                                                    const int* __restrict__ flagp) {
  const int flag = *flagp;
  for (int c = blockIdx.x * 256 + threadIdx.x; c < total_chunks; c += gridDim.x * 256) {
    int s = 0;
    while (c >= (int)a.cum[s]) ++s;
    unsigned int base = s ? a.cum[s - 1] : 0u;
    size_t e = (size_t)(c - base) * 8;
    if (flag) {
      const float* in = (const float*)a.in[s] + e;
      float4 v0 = *(const float4*)in;
      float4 v1 = *(const float4*)(in + 4);
      *(uint4*)(a.out[s] + e) = packbf(v0, v1);
    } else {
      *(uint4*)(a.out[s] + e) = *(const uint4*)((const unsigned short*)a.in[s] + e);
    }
  }
}

// ---------- zero d_out (fallback path only) ----------
__global__ __launch_bounds__(256) void zero_kernel(void* __restrict__ out, int out_elems,
                                                   const int* __restrict__ flagp) {
  int limit = (*flagp) ? (out_elems >> 2) : (out_elems >> 3);  // uint4 chunks
  int i = blockIdx.x * 256 + threadIdx.x;
  if (i < limit) ((uint4*)out)[i] = make_uint4(0, 0, 0, 0);
}

// ---------- split-K partial reduce: d_out = sum_z part[z] + bias + res(mid) ----------
__global__ __launch_bounds__(256) void reduce_kernel(const float* __restrict__ part,
                                                     const unsigned short* __restrict__ mid,
                                                     const void* __restrict__ b1,   // p1_b2 (x rows)
                                                     const void* __restrict__ b2,   // p2_b2 (c rows)
                                                     float* __restrict__ out,
                                                     const int* __restrict__ flagp) {
  if (!*flagp) return;
  const size_t TD = 2097152, LD = (size_t)1536 * 1024, SD = (size_t)512 * 1024;
  size_t i = ((size_t)blockIdx.x * 256 + threadIdx.x) * 4;
  if (i >= TD) return;
  float4 v  = *(const float4*)(part + i);
  float4 v1 = *(const float4*)(part + TD + i);
  float4 v2 = *(const float4*)(part + 2 * TD + i);
  float4 v3 = *(const float4*)(part + 3 * TD + i);
  v.x += v1.x + v2.x + v3.x;
  v.y += v1.y + v2.y + v3.y;
  v.z += v1.z + v2.z + v3.z;
  v.w += v1.w + v2.w + v3.w;
  int col = (int)(i & 1023);
  const float* bias = (const float*)((i < LD) ? b1 : b2);
  size_t ri = (i < LD) ? (SD + i) : (i - LD);
  v.x += bias[col + 0] + bf2f(mid[ri + 0]);
  v.y += bias[col + 1] + bf2f(mid[ri + 1]);
  v.z += bias[col + 2] + bf2f(mid[ri + 2]);
  v.w += bias[col + 3] + bf2f(mid[ri + 3]);
  *(float4*)(out + i) = v;
}

// ---------- LayerNorm over both external inputs -> unified bf16 (c rows first) ----------
__global__ __launch_bounds__(256) void ln_ext_kernel(const void* __restrict__ cin,
                                                     const void* __restrict__ xin,
                                                     unsigned short* __restrict__ out,
                                                     const int* __restrict__ flagp) {
  const int D = 1024, S = 512;
  const int flag = *flagp;
  int row = blockIdx.x;
  const void* src = (row < S) ? cin : xin;
  size_t rb = (size_t)(row < S ? row : row - S) * D;
  int base = threadIdx.x * 4;
  float x0 = loadE(src, rb + base + 0, flag);
  float x1 = loadE(src, rb + base + 1, flag);
  float x2 = loadE(src, rb + base + 2, flag);
  float x3 = loadE(src, rb + base + 3, flag);
  float s1 = x0 + x1 + x2 + x3;
  float s2 = x0 * x0 + x1 * x1 + x2 * x2 + x3 * x3;
  for (int off = 32; off; off >>= 1) {
    s1 += __shfl_down(s1, off, 64);
    s2 += __shfl_down(s2, off, 64);
  }
  __shared__ float red[8];
  int wid = threadIdx.x >> 6;
  if ((threadIdx.x & 63) == 0) { red[wid] = s1; red[4 + wid] = s2; }
  __syncthreads();
  s1 = red[0] + red[1] + red[2] + red[3];
  s2 = red[4] + red[5] + red[6] + red[7];
  float mean = s1 * (1.0f / D);
  float var = s2 * (1.0f / D) - mean * mean;
  float inv = rsqrtf(var + 1e-6f);
  unsigned short* dst = out + (size_t)row * D + base;
  dst[0] = f2bf((x0 - mean) * inv);
  dst[1] = f2bf((x1 - mean) * inv);
  dst[2] = f2bf((x2 - mean) * inv);
  dst[3] = f2bf((x3 - mean) * inv);
}

// ---------- LayerNorm over internal bf16 mid; split outputs ----------
__global__ __launch_bounds__(256) void ln_mid_kernel(const unsigned short* __restrict__ in,
                                                     unsigned short* __restrict__ outc,
                                                     unsigned short* __restrict__ outx) {
  const int D = 1024, S = 512;
  int row = blockIdx.x;
  const unsigned short* src = in + (size_t)row * D;
  int base = threadIdx.x * 4;
  float x0 = bf2f(src[base + 0]);
  float x1 = bf2f(src[base + 1]);
  float x2 = bf2f(src[base + 2]);
  float x3 = bf2f(src[base + 3]);
  float s1 = x0 + x1 + x2 + x3;
  float s2 = x0 * x0 + x1 * x1 + x2 * x2 + x3 * x3;
  for (int off = 32; off; off >>= 1) {
    s1 += __shfl_down(s1, off, 64);
    s2 += __shfl_down(s2, off, 64);
  }
  __shared__ float red[8];
  int wid = threadIdx.x >> 6;
  if ((threadIdx.x & 63) == 0) { red[wid] = s1; red[4 + wid] = s2; }
  __syncthreads();
  s1 = red[0] + red[1] + red[2] + red[3];
  s2 = red[4] + red[5] + red[6] + red[7];
  float mean = s1 * (1.0f / D);
  float var = s2 * (1.0f / D) - mean * mean;
  float inv = rsqrtf(var + 1e-6f);
  unsigned short* dst = (row < S ? outc + (size_t)row * D : outx + (size_t)(row - S) * D) + base;
  dst[0] = f2bf((x0 - mean) * inv);
  dst[1] = f2bf((x1 - mean) * inv);
  dst[2] = f2bf((x2 - mean) * inv);
  dst[3] = f2bf((x3 - mean) * inv);
}

// ---------- multi-descriptor GEMM ----------
// BBF16=1: gload_lds staging, TRIPLE-buffered LDS, counted s_waitcnt vmcnt(4)
// (T3/T4): iteration t waits only for tile t's 4 DMAs (tile t+1's stay in flight),
// barriers, issues tile t+2 into the buffer compute(t-1) just freed, computes.
// Round-7's FBAR drained vmcnt to 0 against loads issued ~260cyc earlier ->
// ~300-600cyc stall/tile; now every load has ~2 tile-times to land.
// XOR-chunk swizzle both-sides involution as round 6 (verified by counters).
// tmask bit d: OUT_MODE 0 store transposed (V^T for attn).
struct GArgs {
  const unsigned short* A[4];
  const void* B[4];
  const void* bias[4];
  const void* res[4];
  void* C[4];
  unsigned long long oo[4];
  int mcum[4];  // cumulative m-tile counts
  int N[4];
  int K;
  int nd;
  int tmask;
  float* part;  // split-K partial base (OUT_MODE 3), slice stride 2048*1024
};

#define BAR() asm volatile("s_waitcnt lgkmcnt(0)\n\ts_barrier" ::: "memory")
#define FBAR() asm volatile("s_waitcnt vmcnt(0) lgkmcnt(0)\n\ts_barrier" ::: "memory")
// counted wait: oldest stage (4 gl16) complete, newer stage may stay in flight
#define CBAR4() asm volatile("s_waitcnt vmcnt(4) lgkmcnt(0)\n\ts_barrier" ::: "memory")

template <int RES_MODE, int OUT_MODE, int SPLITK, int BBF16>
__global__ __launch_bounds__(256) void gemm_kernel(GArgs g, const int* __restrict__ flagp) {
  const int flag = *flagp;
  int by = blockIdx.y;
  int d = 0;
  while (d < g.nd - 1 && by >= g.mcum[d]) ++d;
  int mbase = (d == 0) ? 0 : g.mcum[d - 1];
  const int m0 = (by - mbase) * 128;
  const int N = g.N[d];
  const int n0 = blockIdx.x * 128;
  if (n0 >= N) return;  // block-uniform
  const int K = g.K;
  int kbeg = 0, kend = K;
  if (SPLITK > 1) {
    if (!flag) {
      if (blockIdx.z != 0) return;
    } else {
      int kl = K / SPLITK;
      kbeg = blockIdx.z * kl;
      kend = kbeg + kl;
    }
  }
  const int nt = (kend - kbeg) >> 5;

  constexpr int NBUF = BBF16 ? 3 : 2;
  constexpr int BSTRIDE = BBF16 ? 4096 : 5120;
  __shared__ __align__(16) unsigned short sA[NBUF * BSTRIDE];
  __shared__ __align__(16) unsigned short sB[NBUF * BSTRIDE];

  const int tid = threadIdx.x;
  const int lane = tid & 63;
  const int wave = tid >> 6;
  const int wm = (wave >> 1) * 64, wn = (wave & 1) * 64;
  const int srow = tid >> 2;
  const int scol = BBF16 ? ((((tid & 3) ^ ((tid >> 3) & 3))) * 8) : ((tid & 3) * 8);
  const unsigned short* Ag0 = g.A[d] + (size_t)(m0 + srow) * K + kbeg + scol;
  const unsigned short* Ag1 = Ag0 + (size_t)64 * K;
  const unsigned short* Bh0 = (const unsigned short*)g.B[d] + (size_t)(n0 + srow) * K + kbeg + scol;
  const unsigned short* Bh1 = Bh0 + (size_t)64 * K;

  const int fr = lane & 15;
  const int rdo = BBF16 ? ((((lane >> 4) ^ ((fr >> 1) & 3))) * 8) : ((lane >> 4) * 8);
  constexpr int PITCH = BBF16 ? 32 : 40;
  floatx4 acc[4][4] = {};
  auto compute = [&](const unsigned short* as, const unsigned short* bs) {
    short8 af[4], bfr[4];
    #pragma unroll
    for (int i = 0; i < 4; ++i) {
      af[i]  = *(const short8*)(as + (wm + i * 16 + fr) * PITCH + rdo);
      bfr[i] = *(const short8*)(bs + (wn + i * 16 + fr) * PITCH + rdo);
    }
    #pragma unroll
    for (int mi = 0; mi < 4; ++mi)
      #pragma unroll
      for (int ni = 0; ni < 4; ++ni)
        acc[mi][ni] = __builtin_amdgcn_mfma_f32_16x16x32_bf16(af[mi], bfr[ni], acc[mi][ni], 0, 0, 0);
  };

  if (BBF16) {
    unsigned short* lA0 = sA + wave * 512;
    unsigned short* lA1 = lA0 + 2048;
    unsigned short* lB0 = sB + wave * 512;
    unsigned short* lB1 = lB0 + 2048;
    auto stage = [&](int buf, int kk) {
      int bo = buf * 4096;
      gl16(Ag0 + kk, lA0 + bo);
      gl16(Ag1 + kk, lA1 + bo);
      gl16(Bh0 + kk, lB0 + bo);
      gl16(Bh1 + kk, lB1 + bo);
    };
    // prologue: tiles 0,1 into buffers 0,1 (8 loads in flight)
    stage(0, 0);
    if (nt > 1) stage(1, 32);
    int b = 0;  // t % 3
    for (int t = 0; t < nt; ++t) {
      if (t + 1 < nt) CBAR4();   // tile t landed; tile t+1's 4 stay in flight
      else            FBAR();    // nothing beyond t: full drain
      int b2 = (b >= 1) ? b - 1 : 2;  // (t+2) % 3
      if (t + 2 < nt) stage(b2, (t + 2) * 32);  // buffer freed by compute(t-1)
      compute(sA + b * 4096, sB + b * 4096);
      b = (b == 2) ? 0 : b + 1;
    }
  } else {
    const float* Bf0 = (const float*)g.B[d] + (size_t)(n0 + srow) * K + kbeg + scol;
    const float* Bf1 = Bf0 + (size_t)64 * K;
    const int wo0 = srow * 40 + scol;
    const int wo1 = wo0 + 64 * 40;
    uint4 ra0, ra1, rb0, rb1;
    auto load_tile = [&](int kk) {
      ra0 = *(const uint4*)(Ag0 + kk);
      ra1 = *(const uint4*)(Ag1 + kk);
      if (!flag) {
        rb0 = *(const uint4*)(Bh0 + kk);
        rb1 = *(const uint4*)(Bh1 + kk);
      } else {
        float4 x0 = *(const float4*)(Bf0 + kk), x1 = *(const float4*)(Bf0 + kk + 4);
        float4 y0 = *(const float4*)(Bf1 + kk), y1 = *(const float4*)(Bf1 + kk + 4);
        rb0 = packbf(x0, x1);
        rb1 = packbf(y0, y1);
      }
    };
    auto store_tile = [&](int buf) {
      unsigned short* sa = sA + buf * 5120;
      unsigned short* sb = sB + buf * 5120;
      *(uint4*)(sa + wo0) = ra0;
      *(uint4*)(sa + wo1) = ra1;
      *(uint4*)(sb + wo0) = rb0;
      *(uint4*)(sb + wo1) = rb1;
    };
    load_tile(0);
    store_tile(0);
    if (nt > 1) load_tile(32);
    BAR();
    for (int t = 0; t < nt; ++t) {
      if (t + 1 < nt) {
        store_tile((t + 1) & 1);
        if (t + 2 < nt) load_tile((t + 2) * 32);
      }
      compute(sA + (t & 1) * 5120, sB + (t & 1) * 5120);
      if (t + 1 < nt) BAR();
    }
  }

  const void* bias = g.bias[d];
  const void* res = g.res[d];
  void* C = g.C[d];
  const size_t oo = g.oo[d];
  const bool first = (SPLITK <= 1) || (blockIdx.z == 0) || !flag;
  const bool rawpart = (OUT_MODE == 3) && (flag != 0);
  const bool trans = (OUT_MODE == 0) && (((g.tmask) >> d) & 1);
  #pragma unroll
  for (int mi = 0; mi < 4; ++mi)
    #pragma unroll
    for (int ni = 0; ni < 4; ++ni) {
      int colb = n0 + wn + ni * 16 + (lane & 15);
      int rowb = m0 + wm + mi * 16 + (lane >> 4) * 4;
      if (trans) {
        ushortx4 o4;
        #pragma unroll
        for (int r = 0; r < 4; ++r) {
          float val = acc[mi][ni][r];
          if (bias) val += loadE(bias, (size_t)colb, flag);
          o4[r] = f2bf(val);
        }
        *(ushortx4*)((unsigned short*)C + (size_t)colb * 2048 + oo + rowb) = o4;
      } else {
        #pragma unroll
        for (int r = 0; r < 4; ++r) {
          int row = rowb + r;
          int col = colb;
          float val = acc[mi][ni][r];
          size_t off = (size_t)row * N + col;
          if (first && !rawpart) {
            if (bias) val += loadE(bias, (size_t)col, flag);
            if (RES_MODE == 1) val += loadE(res, off, flag);
            if (RES_MODE == 3) {
              float h1v = bf2f(((const unsigned short*)res)[off]);
              val = (h1v / (1.0f + __expf(-h1v))) * val;
            }
            if (RES_MODE == 4) val += bf2f(((const unsigned short*)res)[off]);
          }
          if (OUT_MODE == 0) {
            ((unsigned short*)C)[off] = f2bf(val);
          } else if (OUT_MODE == 3) {
            if (flag) g.part[(size_t)blockIdx.z * 2097152 + oo + off] = val;
            else      ((unsigned short*)C)[oo + off] = f2bf(val);
          } else {  // OUT_MODE == 2 (fallback)
            if (flag) {
              if (SPLITK > 1) atomicAdd((float*)C + oo + off, val);
              else            ((float*)C)[oo + off] = val;
            } else {
              ((unsigned short*)C)[oo + off] = f2bf(val);
            }
          }
        }
      }
    }
}

// ---------- per-(t,head) RMSNorm + RoPE, 4 heads/block, in place ----------
__global__ __launch_bounds__(256) void rmsrope_kernel(
    unsigned short* __restrict__ qk,
    const void* __restrict__ qn_c, const void* __restrict__ kn_c,
    const void* __restrict__ qn_x, const void* __restrict__ kn_x,
    const void* __restrict__ freqs, const int* __restrict__ flagp) {
  const int flag = *flagp;
  int t = blockIdx.x;
  int h = blockIdx.y * 4 + (threadIdx.x >> 6);
  int d = threadIdx.x & 63;
  unsigned short* qrow = qk + (size_t)t * 2048 + h * 64;
  unsigned short* krow = qrow + 1024;
  float q = bf2f(qrow[d]), k = bf2f(krow[d]);
  float qs = q * q, ks = k * k;
  for (int off = 32; off; off >>= 1) {
    qs += __shfl_xor(qs, off, 64);
    ks += __shfl_xor(ks, off, 64);
  }
  const void* qn = (t < 512) ? qn_c : qn_x;
  const void* kn = (t < 512) ? kn_c : kn_x;
  q = q * rsqrtf(qs * (1.0f / 64.0f) + 1e-6f) * loadE(qn, d, flag);
  k = k * rsqrtf(ks * (1.0f / 64.0f) + 1e-6f) * loadE(kn, d, flag);
  int j = d >> 1;
  float cv = loadE(freqs, (size_t)(t * 32 + j) * 2 + 0, flag);
  float sv = loadE(freqs, (size_t)(t * 32 + j) * 2 + 1, flag);
  float qo = __shfl_xor(q, 1, 64);
  float ko = __shfl_xor(k, 1, 64);
  float qn2, kn2;
  if ((d & 1) == 0) { qn2 = q * cv - qo * sv; kn2 = k * cv - ko * sv; }
  else              { qn2 = qo * sv + q * cv; kn2 = ko * sv + k * cv; }
  qrow[d] = f2bf(qn2);
  krow[d] = f2bf(kn2);
}

// ---------- MFMA flash attention (round-7 staging + mask skip) ----------
__global__ __launch_bounds__(256) void attn_kernel(const unsigned short* __restrict__ qk,
                                                   const unsigned short* __restrict__ vT,
                                                   unsigned short* __restrict__ y) {
  int id = blockIdx.x;
  int blk = (id & 256) ? (31 - (id & 31)) : (id & 31);
  int h = (id >> 5) & 15;
  int wv = threadIdx.x >> 6;
  int lane = threadIdx.x & 63;
  int qbase = blk * 64 + wv * 16;

  __shared__ __align__(16) unsigned short Ks[2 * 4096];  // [buf][key][64 d] swz
  __shared__ __align__(16) unsigned short Vs[2 * 4096];  // [buf][d][64 key] swz
  __shared__ __align__(16) unsigned short ps[4][16 * 72];

  const int c0 = wv * 64 + lane;
  const int r0 = c0 >> 3,         k0 = (c0 & 7) ^ (r0 & 7);
  const int r1 = (c0 + 256) >> 3, k1 = (c0 & 7) ^ (r1 & 7);
  unsigned short* kd0 = Ks + wv * 512;
  unsigned short* kd1 = Ks + 2048 + wv * 512;
  unsigned short* vd0 = Vs + wv * 512;
  unsigned short* vd1 = Vs + 2048 + wv * 512;
  const unsigned short* kgp0 = qk + 1024 + h * 64 + k0 * 8 + (size_t)r0 * 2048;
  const unsigned short* kgp1 = qk + 1024 + h * 64 + k1 * 8 + (size_t)r1 * 2048;
  const unsigned short* vgp0 = vT + (size_t)(h * 64 + r0) * 2048 + k0 * 8;
  const unsigned short* vgp1 = vT + (size_t)(h * 64 + r1) * 2048 + k1 * 8;
  auto stage = [&](int buf, int j0) {
    int bo = buf * 4096;
    gl16(kgp0 + (size_t)j0 * 2048, kd0 + bo);
    gl16(kgp1 + (size_t)j0 * 2048, kd1 + bo);
    gl16(vgp0 + j0, vd0 + bo);
    gl16(vgp1 + j0, vd1 + bo);
  };

  short8 qa[2];
  {
    int m = lane & 15, dj = (lane >> 4) * 8;
    const unsigned short* qp = qk + (size_t)(qbase + m) * 2048 + h * 64 + dj;
    qa[0] = *(const short8*)(qp);
    qa[1] = *(const short8*)(qp + 32);
  }
  floatx4 o[4] = {};
  float mrow[4] = {-1e30f, -1e30f, -1e30f, -1e30f};
  float lrow[4] = {0.f, 0.f, 0.f, 0.f};
  int ntiles = blk + 1;

  stage(0, 0);
  FBAR();
  for (int tile = 0; tile < ntiles; ++tile) {
    int j0 = tile * 64;
    if (tile + 1 < ntiles) stage((tile + 1) & 1, j0 + 64);
    const unsigned short* Kb = Ks + (tile & 1) * 4096;
    const unsigned short* Vb = Vs + (tile & 1) * 4096;
    floatx4 sacc[4];
    #pragma unroll
    for (int kg = 0; kg < 4; ++kg) {
      floatx4 z = {0.f, 0.f, 0.f, 0.f};
      #pragma unroll
      for (int kc = 0; kc < 2; ++kc) {
        int kr = kg * 16 + (lane & 15);
        int p = (kc * 4 + (lane >> 4)) ^ (kr & 7);
        short8 kb = *(const short8*)(Kb + kr * 64 + p * 8);
        z = __builtin_amdgcn_mfma_f32_16x16x32_bf16(qa[kc], kb, z, 0, 0, 0);
      }
      sacc[kg] = z;
    }
    // causal mask only needed on the diagonal tile (wave-uniform branch)
    if (tile == blk) {
      #pragma unroll
      for (int kg = 0; kg < 4; ++kg)
        #pragma unroll
        for (int r = 0; r < 4; ++r) {
          int key_g = j0 + kg * 16 + (lane & 15);
          int q_g = qbase + (lane >> 4) * 4 + r;
          float s = sacc[kg][r] * 0.125f;
          sacc[kg][r] = (key_g <= q_g) ? s : -1e30f;
        }
    } else {
      #pragma unroll
      for (int kg = 0; kg < 4; ++kg)
        #pragma unroll
        for (int r = 0; r < 4; ++r) sacc[kg][r] *= 0.125f;
    }
    #pragma unroll
    for (int r = 0; r < 4; ++r) {
      float mx = fmaxf(fmaxf(sacc[0][r], sacc[1][r]), fmaxf(sacc[2][r], sacc[3][r]));
      mx = fmaxf(mx, __shfl_xor(mx, 1, 64));
      mx = fmaxf(mx, __shfl_xor(mx, 2, 64));
      mx = fmaxf(mx, __shfl_xor(mx, 4, 64));
      mx = fmaxf(mx, __shfl_xor(mx, 8, 64));
      float mnew = fmaxf(mrow[r], mx);
      float al = __expf(mrow[r] - mnew);
      mrow[r] = mnew;
      float sum = 0.f;
      #pragma unroll
      for (int kg = 0; kg < 4; ++kg) {
        float p = __expf(sacc[kg][r] - mnew);
        sacc[kg][r] = p;
        sum += p;
      }
      sum += __shfl_xor(sum, 1, 64);
      sum += __shfl_xor(sum, 2, 64);
      sum += __shfl_xor(sum, 4, 64);
      sum += __shfl_xor(sum, 8, 64);
      lrow[r] = lrow[r] * al + sum;
      #pragma unroll
      for (int ni = 0; ni < 4; ++ni) o[ni][r] *= al;
    }
    unsigned short* pw = ps[wv];
    #pragma unroll
    for (int kg = 0; kg < 4; ++kg)
      #pragma unroll
      for (int r = 0; r < 4; ++r)
        pw[((lane >> 4) * 4 + r) * 72 + kg * 16 + (lane & 15)] = f2bf(sacc[kg][r]);
    asm volatile("s_waitcnt lgkmcnt(0)" ::: "memory");
    short8 pa[2];
    pa[0] = *(const short8*)(pw + (lane & 15) * 72 + (lane >> 4) * 8);
    pa[1] = *(const short8*)(pw + (lane & 15) * 72 + 32 + (lane >> 4) * 8);
    #pragma unroll
    for (int ni = 0; ni < 4; ++ni) {
      floatx4 z = o[ni];
      int dd = ni * 16 + (lane & 15);
      #pragma unroll
      for (int kc = 0; kc < 2; ++kc) {
        int p = (kc * 4 + (lane >> 4)) ^ (dd & 7);
        short8 vb = *(const short8*)(Vb + dd * 64 + p * 8);
        z = __builtin_amdgcn_mfma_f32_16x16x32_bf16(pa[kc], vb, z, 0, 0, 0);
      }
      o[ni] = z;
    }
    if (tile + 1 < ntiles) FBAR();
  }
  #pragma unroll
  for (int ni = 0; ni < 4; ++ni)
    #pragma unroll
    for (int r = 0; r < 4; ++r) {
      int q = qbase + (lane >> 4) * 4 + r;
      int dd = ni * 16 + (lane & 15);
      y[(size_t)q * 1024 + h * 64 + dd] = f2bf(o[ni][r] / lrow[r]);
    }
}

extern "C" void kernel_launch(void* const* d_in, const int* in_sizes, int n_in,
                              void* d_out, int out_size, void* d_ws, size_t ws_size,
                              hipStream_t stream) {
  const int L = 1536, S = 512, D = 1024, T = 2048, FF = 4096;
  const void* x        = d_in[0];
  const void* c        = d_in[1];
  const void* freqs    = d_in[2];
  const void* px_qk_w  = d_in[3];
  const void* px_qn    = d_in[4];
  const void* px_kn    = d_in[5];
  const void* px_v_w   = d_in[6];
  const void* px_v_b   = d_in[7];
  const void* pc_qk_w  = d_in[8];
  const void* pc_qn    = d_in[9];
  const void* pc_kn    = d_in[10];
  const void* pc_v_w   = d_in[11];
  const void* pc_v_b   = d_in[12];
  const void* p1_proj_w = d_in[13];
  const void* p1_proj_b = d_in[14];
  const void* p1_w1 = d_in[15];
  const void* p1_b1 = d_in[16];
  const void* p1_w3 = d_in[17];
  const void* p1_b3 = d_in[18];
  const void* p1_w2 = d_in[19];
  const void* p1_b2 = d_in[20];
  const void* p2_proj_w = d_in[21];
  const void* p2_proj_b = d_in[22];
  const void* p2_w1 = d_in[23];
  const void* p2_b1 = d_in[24];
  const void* p2_w3 = d_in[25];
  const void* p2_b3 = d_in[26];
  const void* p2_w2 = d_in[27];
  const void* p2_b2 = d_in[28];

  char* ws = (char*)d_ws;
  unsigned short* hln     = (unsigned short*)(ws);
  unsigned short* ybuf    = (unsigned short*)(ws);
  unsigned short* h1c     = (unsigned short*)(ws);
  unsigned short* qkbuf   = (unsigned short*)(ws + ((size_t)4  << 20));
  unsigned short* h1x     = (unsigned short*)(ws + ((size_t)4  << 20));
  unsigned short* vbufT   = (unsigned short*)(ws + ((size_t)12 << 20));
  unsigned short* mid     = (unsigned short*)(ws + ((size_t)16 << 20));
  unsigned short* midln_c = (unsigned short*)(ws + ((size_t)20 << 20));
  int*            flag    = (int*)(ws + ((size_t)21 << 20));
  unsigned short* midln_x = (unsigned short*)d_out;
  unsigned short* hlnx    = hln + (size_t)S * D;

  const bool conv = ws_size >= ((size_t)90 << 20);
  unsigned short* wbf = (unsigned short*)(ws + ((size_t)24 << 20));
  unsigned short* b_qk_c = wbf + 0;
  unsigned short* b_qk_x = wbf + 2097152;
  unsigned short* b_v_c  = wbf + 4194304;
  unsigned short* b_v_x  = wbf + 5242880;
  unsigned short* b_pj1  = wbf + 6291456;
  unsigned short* b_pj2  = wbf + 7340032;
  unsigned short* b_w1p1 = wbf + 8388608;
  unsigned short* b_w1p2 = wbf + 12582912;
  unsigned short* b_w3p1 = wbf + 16777216;
  unsigned short* b_w3p2 = wbf + 20971520;
  unsigned short* b_w2p1 = wbf + 25165824;
  unsigned short* b_w2p2 = wbf + 29360128;
  float* part = (float*)(ws + ((size_t)40 << 20));

  detect_kernel<<<1, 64, 0, stream>>>((const unsigned int*)px_qn, flag);

  if (conv) {
    CArgs ca;
    const void* ins[12]   = {pc_qk_w, px_qk_w, pc_v_w, px_v_w, p1_proj_w, p2_proj_w,
                             p1_w1, p2_w1, p1_w3, p2_w3, p1_w2, p2_w2};
    unsigned short* os[12] = {b_qk_c, b_qk_x, b_v_c, b_v_x, b_pj1, b_pj2,
                              b_w1p1, b_w1p2, b_w3p1, b_w3p2, b_w2p1, b_w2p2};
    unsigned int cnt[12]  = {262144, 262144, 131072, 131072, 131072, 131072,
                             524288, 524288, 524288, 524288, 524288, 524288};
    unsigned int cum = 0;
    for (int i = 0; i < 12; ++i) { ca.in[i] = ins[i]; ca.out[i] = os[i]; cum += cnt[i]; ca.cum[i] = cum; }
    convw_kernel<<<2048, 256, 0, stream>>>(ca, (int)cum, flag);
  }

  ln_ext_kernel<<<T, 256, 0, stream>>>(c, x, hln, flag);

  // P1: QKV (4 descriptors). V descs (2,3) store TRANSPOSED into vbufT (tmask).
  {
    GArgs g = {};
    g.A[0] = hln;  g.bias[0] = nullptr; g.C[0] = qkbuf;                    g.mcum[0] = 4;  g.N[0] = 2048;
    g.A[1] = hlnx; g.bias[1] = nullptr; g.C[1] = qkbuf + (size_t)S * 2048; g.mcum[1] = 16; g.N[1] = 2048;
    g.A[2] = hln;  g.bias[2] = pc_v_b;  g.C[2] = vbufT; g.oo[2] = 0;       g.mcum[2] = 20; g.N[2] = 1024;
    g.A[3] = hlnx; g.bias[3] = px_v_b;  g.C[3] = vbufT; g.oo[3] = S;       g.mcum[3] = 32; g.N[3] = 1024;
    g.K = 1024; g.nd = 4; g.tmask = 0b1100;
    if (conv) {
      g.B[0] = b_qk_c; g.B[1] = b_qk_x; g.B[2] = b_v_c; g.B[3] = b_v_x;
      gemm_kernel<0, 0, 1, 1><<<dim3(16, 32), 256, 0, stream>>>(g, flag);
    } else {
      g.B[0] = pc_qk_w; g.B[1] = px_qk_w; g.B[2] = pc_v_w; g.B[3] = px_v_w;
      gemm_kernel<0, 0, 1, 0><<<dim3(16, 32), 256, 0, stream>>>(g, flag);
    }
  }
  rmsrope_kernel<<<dim3(T, 4), 256, 0, stream>>>(qkbuf, pc_qn, pc_kn, px_qn, px_kn, freqs, flag);
  attn_kernel<<<512, 256, 0, stream>>>(qkbuf, vbufT, ybuf);

  // P2: out-projection + external residual -> mid
  {
    GArgs g = {};
    g.A[0] = ybuf;                  g.bias[0] = p2_proj_b; g.res[0] = c; g.C[0] = mid;                  g.mcum[0] = 4;  g.N[0] = 1024;
    g.A[1] = ybuf + (size_t)S * D;  g.bias[1] = p1_proj_b; g.res[1] = x; g.C[1] = mid + (size_t)S * D;  g.mcum[1] = 16; g.N[1] = 1024;
    g.K = 1024; g.nd = 2;
    if (conv) {
      g.B[0] = b_pj2; g.B[1] = b_pj1;
      gemm_kernel<1, 0, 1, 1><<<dim3(8, 16), 256, 0, stream>>>(g, flag);
    } else {
      g.B[0] = p2_proj_w; g.B[1] = p1_proj_w;
      gemm_kernel<1, 0, 1, 0><<<dim3(8, 16), 256, 0, stream>>>(g, flag);
    }
  }
  ln_mid_kernel<<<T, 256, 0, stream>>>(mid, midln_c, midln_x);

  // P3: W1 (x + c merged)
  {
    GArgs g = {};
    g.A[0] = midln_x; g.bias[0] = p1_b1; g.C[0] = h1x; g.mcum[0] = 12; g.N[0] = 4096;
    g.A[1] = midln_c; g.bias[1] = p2_b1; g.C[1] = h1c; g.mcum[1] = 16; g.N[1] = 4096;
    g.K = 1024; g.nd = 2;
    if (conv) {
      g.B[0] = b_w1p1; g.B[1] = b_w1p2;
      gemm_kernel<0, 0, 1, 1><<<dim3(32, 16), 256, 0, stream>>>(g, flag);
    } else {
      g.B[0] = p1_w1; g.B[1] = p2_w1;
      gemm_kernel<0, 0, 1, 0><<<dim3(32, 16), 256, 0, stream>>>(g, flag);
    }
  }
  // P4: W3 with fused silu(h1)*(acc+bias), in place
  {
    GArgs g = {};
    g.A[0] = midln_x; g.bias[0] = p1_b3; g.res[0] = h1x; g.C[0] = h1x; g.mcum[0] = 12; g.N[0] = 4096;
    g.A[1] = midln_c; g.bias[1] = p2_b3; g.res[1] = h1c; g.C[1] = h1c; g.mcum[1] = 16; g.N[1] = 4096;
    g.K = 1024; g.nd = 2;
    if (conv) {
      g.B[0] = b_w3p1; g.B[1] = b_w3p2;
      gemm_kernel<3, 0, 1, 1><<<dim3(32, 16), 256, 0, stream>>>(g, flag);
    } else {
      g.B[0] = p1_w3; g.B[1] = p2_w3;
      gemm_kernel<3, 0, 1, 0><<<dim3(32, 16), 256, 0, stream>>>(g, flag);
    }
  }
  // P5: W2 split-K=4. conv: raw fp32 partials + reduce. fallback: zero + atomics.
  if (conv) {
    GArgs g = {};
    g.A[0] = h1x; g.bias[0] = p1_b2; g.res[0] = mid + (size_t)S * D; g.C[0] = d_out; g.oo[0] = 0;             g.mcum[0] = 12; g.N[0] = 1024;
    g.A[1] = h1c; g.bias[1] = p2_b2; g.res[1] = mid;                 g.C[1] = d_out; g.oo[1] = (size_t)L * D; g.mcum[1] = 16; g.N[1] = 1024;
    g.K = 4096; g.nd = 2;
    g.part = part;
    g.B[0] = b_w2p1; g.B[1] = b_w2p2;
    gemm_kernel<4, 3, 4, 1><<<dim3(8, 16, 4), 256, 0, stream>>>(g, flag);
    reduce_kernel<<<2048, 256, 0, stream>>>(part, mid, p1_b2, p2_b2, (float*)d_out, flag);
  } else {
    zero_kernel<<<2048, 256, 0, stream>>>(d_out, out_size, flag);
    GArgs g = {};
    g.A[0] = h1x; g.bias[0] = p1_b2; g.res[0] = mid + (size_t)S * D; g.C[0] = d_out; g.oo[0] = 0;             g.mcum[0] = 12; g.N[0] = 1024;
    g.A[1] = h1c; g.bias[1] = p2_b2; g.res[1] = mid;                 g.C[1] = d_out; g.oo[1] = (size_t)L * D; g.mcum[1] = 16; g.N[1] = 1024;
    g.K = 4096; g.nd = 2;
    g.B[0] = p1_w2; g.B[1] = p2_w2;
    gemm_kernel<4, 2, 4, 0><<<dim3(8, 16, 4), 256, 0, stream>>>(g, flag);
  }
}

// Round 10
// 485.605 us; speedup vs baseline: 1.1182x; 1.0206x over previous
//
#include <hip/hip_runtime.h>

typedef __attribute__((ext_vector_type(8))) short short8;
typedef __attribute__((ext_vector_type(4))) float floatx4;
typedef __attribute__((ext_vector_type(4))) unsigned short ushortx4;

// ---------- bf16 helpers ----------
__device__ __forceinline__ float bf2f(unsigned short u) {
  union { unsigned int i; float f; } v; v.i = ((unsigned int)u) << 16; return v.f;
}
__device__ __forceinline__ unsigned short f2bf(float f) {
  union { float f; unsigned int i; } v; v.f = f;
  unsigned int x = v.i + 0x7fffu + ((v.i >> 16) & 1u);
  return (unsigned short)(x >> 16);
}
__device__ __forceinline__ float loadE(const void* p, size_t i, int f) {
  return f ? ((const float*)p)[i] : bf2f(((const unsigned short*)p)[i]);
}
__device__ __forceinline__ uint4 packbf(float4 a, float4 b) {
  union { unsigned short u[8]; uint4 v; } p;
  p.u[0] = f2bf(a.x); p.u[1] = f2bf(a.y); p.u[2] = f2bf(a.z); p.u[3] = f2bf(a.w);
  p.u[4] = f2bf(b.x); p.u[5] = f2bf(b.y); p.u[6] = f2bf(b.z); p.u[7] = f2bf(b.w);
  return p.v;
}

// async global->LDS, 16B per lane. LDS dest = wave-uniform base + lane*16.
__device__ __forceinline__ void gl16(const unsigned short* g, unsigned short* l) {
  __builtin_amdgcn_global_load_lds(
      (const __attribute__((address_space(1))) void*)g,
      (__attribute__((address_space(3))) void*)l, 16, 0, 0);
}

// ---------- dtype detect ----------
__global__ void detect_kernel(const unsigned int* __restrict__ probe, int* __restrict__ flag) {
  if (threadIdx.x == 0 && blockIdx.x == 0) *flag = (probe[0] == 0x3F800000u) ? 1 : 0;
}

// ---------- weight conversion -> bf16, block-uniform segments ----------
// Round-10 fix: old version did a data-dependent while-search PER CHUNK (serial
// scalar chain ahead of every load -> 2.2 TB/s, 60us). All segment sizes are
// multiples of 2048 chunks, so each 256-thread block owns 2048 consecutive
// chunks (8/thread) in exactly ONE segment: search once per block, batch the 8
// loads before the 8 pack/stores.
struct CArgs {
  const void* in[12];
  unsigned short* out[12];
  unsigned int cum[12];  // cumulative chunk counts (chunk = 8 elems), sentinel-filled
};
__global__ __launch_bounds__(256) void convw_kernel(CArgs a, const int* __restrict__ flagp) {
  const int flag = *flagp;
  int bc = blockIdx.x * 2048;  // first chunk of this block
  int s = 0;
  while (bc >= (int)a.cum[s]) ++s;
  int base = s ? (int)a.cum[s - 1] : 0;
  size_t e0 = ((size_t)(bc - base) + threadIdx.x) * 8;
  if (flag) {
    const float* in = (const float*)a.in[s];
    unsigned short* out = a.out[s];
    float4 v0[8], v1[8];
    #pragma unroll
    for (int k = 0; k < 8; ++k) {
      size_t e = e0 + (size_t)k * 2048;
      v0[k] = *(const float4*)(in + e);
      v1[k] = *(const float4*)(in + e + 4);
    }
    #pragma unroll
    for (int k = 0; k < 8; ++k)
      *(uint4*)(out + e0 + (size_t)k * 2048) = packbf(v0[k], v1[k]);
  } else {
    const unsigned short* in = (const unsigned short*)a.in[s];
    unsigned short* out = a.out[s];
    #pragma unroll
    for (int k = 0; k < 8; ++k) {
      size_t e = e0 + (size_t)k * 2048;
      *(uint4*)(out + e) = *(const uint4*)(in + e);
    }
  }
}

// ---------- zero d_out (fallback path only) ----------
__global__ __launch_bounds__(256) void zero_kernel(void* __restrict__ out, int out_elems,
                                                   const int* __restrict__ flagp) {
  int limit = (*flagp) ? (out_elems >> 2) : (out_elems >> 3);  // uint4 chunks
  int i = blockIdx.x * 256 + threadIdx.x;
  if (i < limit) ((uint4*)out)[i] = make_uint4(0, 0, 0, 0);
}

// ---------- P5 split-K reduce: d_out = sum_z part[z] + bias + res(mid) ----------
__global__ __launch_bounds__(256) void reduce_kernel(const float* __restrict__ part,
                                                     const unsigned short* __restrict__ mid,
                                                     const void* __restrict__ b1,   // p1_b2 (x rows)
                                                     const void* __restrict__ b2,   // p2_b2 (c rows)
                                                     float* __restrict__ out,
                                                     const int* __restrict__ flagp) {
  if (!*flagp) return;
  const size_t TD = 2097152, LD = (size_t)1536 * 1024, SD = (size_t)512 * 1024;
  size_t i = ((size_t)blockIdx.x * 256 + threadIdx.x) * 4;
  if (i >= TD) return;
  float4 v  = *(const float4*)(part + i);
  float4 v1 = *(const float4*)(part + TD + i);
  float4 v2 = *(const float4*)(part + 2 * TD + i);
  float4 v3 = *(const float4*)(part + 3 * TD + i);
  v.x += v1.x + v2.x + v3.x;
  v.y += v1.y + v2.y + v3.y;
  v.z += v1.z + v2.z + v3.z;
  v.w += v1.w + v2.w + v3.w;
  int col = (int)(i & 1023);
  const float* bias = (const float*)((i < LD) ? b1 : b2);
  size_t ri = (i < LD) ? (SD + i) : (i - LD);
  v.x += bias[col + 0] + bf2f(mid[ri + 0]);
  v.y += bias[col + 1] + bf2f(mid[ri + 1]);
  v.z += bias[col + 2] + bf2f(mid[ri + 2]);
  v.w += bias[col + 3] + bf2f(mid[ri + 3]);
  *(float4*)(out + i) = v;
}

// ---------- P2 split-K reduce: mid = bf16( sum_z part[z] + bias + external res ) ----------
// Rows 0..511 = c-stream (bias p2_proj_b, res c); rows 512..2047 = x-stream.
__global__ __launch_bounds__(256) void reduce_mid_kernel(const float* __restrict__ part,
                                                         const void* __restrict__ cres,
                                                         const void* __restrict__ xres,
                                                         const float* __restrict__ b_c,
                                                         const float* __restrict__ b_x,
                                                         unsigned short* __restrict__ mid,
                                                         const int* __restrict__ flagp) {
  if (!*flagp) return;  // bf16 path: GEMM slice 0 wrote mid directly
  const size_t TD = 2097152;
  size_t i = ((size_t)blockIdx.x * 256 + threadIdx.x) * 4;
  if (i >= TD) return;
  float4 v  = *(const float4*)(part + i);
  float4 v1 = *(const float4*)(part + TD + i);
  float4 v2 = *(const float4*)(part + 2 * TD + i);
  float4 v3 = *(const float4*)(part + 3 * TD + i);
  v.x += v1.x + v2.x + v3.x;
  v.y += v1.y + v2.y + v3.y;
  v.z += v1.z + v2.z + v3.z;
  v.w += v1.w + v2.w + v3.w;
  int row = (int)(i >> 10), col = (int)(i & 1023);
  const float* bias = (row < 512) ? b_c : b_x;
  const float* res = (row < 512)
      ? (const float*)cres + ((size_t)row << 10) + col
      : (const float*)xres + ((size_t)(row - 512) << 10) + col;
  float4 rv = *(const float4*)res;
  float4 bv = *(const float4*)(bias + col);
  ushortx4 o;
  o[0] = f2bf(v.x + bv.x + rv.x);
  o[1] = f2bf(v.y + bv.y + rv.y);
  o[2] = f2bf(v.z + bv.z + rv.z);
  o[3] = f2bf(v.w + bv.w + rv.w);
  *(ushortx4*)(mid + i) = o;
}

// ---------- LayerNorm over both external inputs -> unified bf16 (c rows first) ----------
__global__ __launch_bounds__(256) void ln_ext_kernel(const void* __restrict__ cin,
                                                     const void* __restrict__ xin,
                                                     unsigned short* __restrict__ out,
                                                     const int* __restrict__ flagp) {
  const int D = 1024, S = 512;
  const int flag = *flagp;
  int row = blockIdx.x;
  const void* src = (row < S) ? cin : xin;
  size_t rb = (size_t)(row < S ? row : row - S) * D;
  int base = threadIdx.x * 4;
  float x0 = loadE(src, rb + base + 0, flag);
  float x1 = loadE(src, rb + base + 1, flag);
  float x2 = loadE(src, rb + base + 2, flag);
  float x3 = loadE(src, rb + base + 3, flag);
  float s1 = x0 + x1 + x2 + x3;
  float s2 = x0 * x0 + x1 * x1 + x2 * x2 + x3 * x3;
  for (int off = 32; off; off >>= 1) {
    s1 += __shfl_down(s1, off, 64);
    s2 += __shfl_down(s2, off, 64);
  }
  __shared__ float red[8];
  int wid = threadIdx.x >> 6;
  if ((threadIdx.x & 63) == 0) { red[wid] = s1; red[4 + wid] = s2; }
  __syncthreads();
  s1 = red[0] + red[1] + red[2] + red[3];
  s2 = red[4] + red[5] + red[6] + red[7];
  float mean = s1 * (1.0f / D);
  float var = s2 * (1.0f / D) - mean * mean;
  float inv = rsqrtf(var + 1e-6f);
  unsigned short* dst = out + (size_t)row * D + base;
  dst[0] = f2bf((x0 - mean) * inv);
  dst[1] = f2bf((x1 - mean) * inv);
  dst[2] = f2bf((x2 - mean) * inv);
  dst[3] = f2bf((x3 - mean) * inv);
}

// ---------- LayerNorm over internal bf16 mid; split outputs ----------
__global__ __launch_bounds__(256) void ln_mid_kernel(const unsigned short* __restrict__ in,
                                                     unsigned short* __restrict__ outc,
                                                     unsigned short* __restrict__ outx) {
  const int D = 1024, S = 512;
  int row = blockIdx.x;
  const unsigned short* src = in + (size_t)row * D;
  int base = threadIdx.x * 4;
  float x0 = bf2f(src[base + 0]);
  float x1 = bf2f(src[base + 1]);
  float x2 = bf2f(src[base + 2]);
  float x3 = bf2f(src[base + 3]);
  float s1 = x0 + x1 + x2 + x3;
  float s2 = x0 * x0 + x1 * x1 + x2 * x2 + x3 * x3;
  for (int off = 32; off; off >>= 1) {
    s1 += __shfl_down(s1, off, 64);
    s2 += __shfl_down(s2, off, 64);
  }
  __shared__ float red[8];
  int wid = threadIdx.x >> 6;
  if ((threadIdx.x & 63) == 0) { red[wid] = s1; red[4 + wid] = s2; }
  __syncthreads();
  s1 = red[0] + red[1] + red[2] + red[3];
  s2 = red[4] + red[5] + red[6] + red[7];
  float mean = s1 * (1.0f / D);
  float var = s2 * (1.0f / D) - mean * mean;
  float inv = rsqrtf(var + 1e-6f);
  unsigned short* dst = (row < S ? outc + (size_t)row * D : outx + (size_t)(row - S) * D) + base;
  dst[0] = f2bf((x0 - mean) * inv);
  dst[1] = f2bf((x1 - mean) * inv);
  dst[2] = f2bf((x2 - mean) * inv);
  dst[3] = f2bf((x3 - mean) * inv);
}

// ---------- multi-descriptor GEMM (round-9 structure) ----------
struct GArgs {
  const unsigned short* A[4];
  const void* B[4];
  const void* bias[4];
  const void* res[4];
  void* C[4];
  unsigned long long oo[4];
  int mcum[4];  // cumulative m-tile counts
  int N[4];
  int K;
  int nd;
  int tmask;
  float* part;  // split-K partial base (OUT_MODE 3), slice stride 2048*1024
};

#define BAR() asm volatile("s_waitcnt lgkmcnt(0)\n\ts_barrier" ::: "memory")
#define FBAR() asm volatile("s_waitcnt vmcnt(0) lgkmcnt(0)\n\ts_barrier" ::: "memory")
// counted wait: oldest stage (4 gl16) complete, newer stage may stay in flight
#define CBAR4() asm volatile("s_waitcnt vmcnt(4) lgkmcnt(0)\n\ts_barrier" ::: "memory")

template <int RES_MODE, int OUT_MODE, int SPLITK, int BBF16>
__global__ __launch_bounds__(256) void gemm_kernel(GArgs g, const int* __restrict__ flagp) {
  const int flag = *flagp;
  int by = blockIdx.y;
  int d = 0;
  while (d < g.nd - 1 && by >= g.mcum[d]) ++d;
  int mbase = (d == 0) ? 0 : g.mcum[d - 1];
  const int m0 = (by - mbase) * 128;
  const int N = g.N[d];
  const int n0 = blockIdx.x * 128;
  if (n0 >= N) return;  // block-uniform
  const int K = g.K;
  int kbeg = 0, kend = K;
  if (SPLITK > 1) {
    if (!flag) {
      if (blockIdx.z != 0) return;
    } else {
      int kl = K / SPLITK;
      kbeg = blockIdx.z * kl;
      kend = kbeg + kl;
    }
  }
  const int nt = (kend - kbeg) >> 5;

  constexpr int NBUF = BBF16 ? 3 : 2;
  constexpr int BSTRIDE = BBF16 ? 4096 : 5120;
  __shared__ __align__(16) unsigned short sA[NBUF * BSTRIDE];
  __shared__ __align__(16) unsigned short sB[NBUF * BSTRIDE];

  const int tid = threadIdx.x;
  const int lane = tid & 63;
  const int wave = tid >> 6;
  const int wm = (wave >> 1) * 64, wn = (wave & 1) * 64;
  const int srow = tid >> 2;
  const int scol = BBF16 ? ((((tid & 3) ^ ((tid >> 3) & 3))) * 8) : ((tid & 3) * 8);
  const unsigned short* Ag0 = g.A[d] + (size_t)(m0 + srow) * K + kbeg + scol;
  const unsigned short* Ag1 = Ag0 + (size_t)64 * K;
  const unsigned short* Bh0 = (const unsigned short*)g.B[d] + (size_t)(n0 + srow) * K + kbeg + scol;
  const unsigned short* Bh1 = Bh0 + (size_t)64 * K;

  const int fr = lane & 15;
  const int rdo = BBF16 ? ((((lane >> 4) ^ ((fr >> 1) & 3))) * 8) : ((lane >> 4) * 8);
  constexpr int PITCH = BBF16 ? 32 : 40;
  floatx4 acc[4][4] = {};
  auto compute = [&](const unsigned short* as, const unsigned short* bs) {
    short8 af[4], bfr[4];
    #pragma unroll
    for (int i = 0; i < 4; ++i) {
      af[i]  = *(const short8*)(as + (wm + i * 16 + fr) * PITCH + rdo);
      bfr[i] = *(const short8*)(bs + (wn + i * 16 + fr) * PITCH + rdo);
    }
    #pragma unroll
    for (int mi = 0; mi < 4; ++mi)
      #pragma unroll
      for (int ni = 0; ni < 4; ++ni)
        acc[mi][ni] = __builtin_amdgcn_mfma_f32_16x16x32_bf16(af[mi], bfr[ni], acc[mi][ni], 0, 0, 0);
  };

  if (BBF16) {
    unsigned short* lA0 = sA + wave * 512;
    unsigned short* lA1 = lA0 + 2048;
    unsigned short* lB0 = sB + wave * 512;
    unsigned short* lB1 = lB0 + 2048;
    auto stage = [&](int buf, int kk) {
      int bo = buf * 4096;
      gl16(Ag0 + kk, lA0 + bo);
      gl16(Ag1 + kk, lA1 + bo);
      gl16(Bh0 + kk, lB0 + bo);
      gl16(Bh1 + kk, lB1 + bo);
    };
    // prologue: tiles 0,1 into buffers 0,1 (8 loads in flight)
    stage(0, 0);
    if (nt > 1) stage(1, 32);
    int b = 0;  // t % 3
    for (int t = 0; t < nt; ++t) {
      if (t + 1 < nt) CBAR4();   // tile t landed; tile t+1's 4 stay in flight
      else            FBAR();    // nothing beyond t: full drain
      int b2 = (b >= 1) ? b - 1 : 2;  // (t+2) % 3
      if (t + 2 < nt) stage(b2, (t + 2) * 32);  // buffer freed by compute(t-1)
      compute(sA + b * 4096, sB + b * 4096);
      b = (b == 2) ? 0 : b + 1;
    }
  } else {
    const float* Bf0 = (const float*)g.B[d] + (size_t)(n0 + srow) * K + kbeg + scol;
    const float* Bf1 = Bf0 + (size_t)64 * K;
    const int wo0 = srow * 40 + scol;
    const int wo1 = wo0 + 64 * 40;
    uint4 ra0, ra1, rb0, rb1;
    auto load_tile = [&](int kk) {
      ra0 = *(const uint4*)(Ag0 + kk);
      ra1 = *(const uint4*)(Ag1 + kk);
      if (!flag) {
        rb0 = *(const uint4*)(Bh0 + kk);
        rb1 = *(const uint4*)(Bh1 + kk);
      } else {
        float4 x0 = *(const float4*)(Bf0 + kk), x1 = *(const float4*)(Bf0 + kk + 4);
        float4 y0 = *(const float4*)(Bf1 + kk), y1 = *(const float4*)(Bf1 + kk + 4);
        rb0 = packbf(x0, x1);
        rb1 = packbf(y0, y1);
      }
    };
    auto store_tile = [&](int buf) {
      unsigned short* sa = sA + buf * 5120;
      unsigned short* sb = sB + buf * 5120;
      *(uint4*)(sa + wo0) = ra0;
      *(uint4*)(sa + wo1) = ra1;
      *(uint4*)(sb + wo0) = rb0;
      *(uint4*)(sb + wo1) = rb1;
    };
    load_tile(0);
    store_tile(0);
    if (nt > 1) load_tile(32);
    BAR();
    for (int t = 0; t < nt; ++t) {
      if (t + 1 < nt) {
        store_tile((t + 1) & 1);
        if (t + 2 < nt) load_tile((t + 2) * 32);
      }
      compute(sA + (t & 1) * 5120, sB + (t & 1) * 5120);
      if (t + 1 < nt) BAR();
    }
  }

  const void* bias = g.bias[d];
  const void* res = g.res[d];
  void* C = g.C[d];
  const size_t oo = g.oo[d];
  const bool first = (SPLITK <= 1) || (blockIdx.z == 0) || !flag;
  const bool rawpart = (OUT_MODE == 3) && (flag != 0);
  const bool trans = (OUT_MODE == 0) && (((g.tmask) >> d) & 1);
  #pragma unroll
  for (int mi = 0; mi < 4; ++mi)
    #pragma unroll
    for (int ni = 0; ni < 4; ++ni) {
      int colb = n0 + wn + ni * 16 + (lane & 15);
      int rowb = m0 + wm + mi * 16 + (lane >> 4) * 4;
      if (trans) {
        ushortx4 o4;
        #pragma unroll
        for (int r = 0; r < 4; ++r) {
          float val = acc[mi][ni][r];
          if (bias) val += loadE(bias, (size_t)colb, flag);
          o4[r] = f2bf(val);
        }
        *(ushortx4*)((unsigned short*)C + (size_t)colb * 2048 + oo + rowb) = o4;
      } else {
        #pragma unroll
        for (int r = 0; r < 4; ++r) {
          int row = rowb + r;
          int col = colb;
          float val = acc[mi][ni][r];
          size_t off = (size_t)row * N + col;
          if (first && !rawpart) {
            if (bias) val += loadE(bias, (size_t)col, flag);
            if (RES_MODE == 1) val += loadE(res, off, flag);
            if (RES_MODE == 3) {
              float h1v = bf2f(((const unsigned short*)res)[off]);
              val = (h1v / (1.0f + __expf(-h1v))) * val;
            }
            if (RES_MODE == 4) val += bf2f(((const unsigned short*)res)[off]);
          }
          if (OUT_MODE == 0) {
            ((unsigned short*)C)[off] = f2bf(val);
          } else if (OUT_MODE == 3) {
            if (flag) g.part[(size_t)blockIdx.z * 2097152 + oo + off] = val;
            else      ((unsigned short*)C)[oo + off] = f2bf(val);
          } else {  // OUT_MODE == 2 (fallback)
            if (flag) {
              if (SPLITK > 1) atomicAdd((float*)C + oo + off, val);
              else            ((float*)C)[oo + off] = val;
            } else {
              ((unsigned short*)C)[oo + off] = f2bf(val);
            }
          }
        }
      }
    }
}

// ---------- per-(t,head) RMSNorm + RoPE, 4 heads/block, in place ----------
__global__ __launch_bounds__(256) void rmsrope_kernel(
    unsigned short* __restrict__ qk,
    const void* __restrict__ qn_c, const void* __restrict__ kn_c,
    const void* __restrict__ qn_x, const void* __restrict__ kn_x,
    const void* __restrict__ freqs, const int* __restrict__ flagp) {
  const int flag = *flagp;
  int t = blockIdx.x;
  int h = blockIdx.y * 4 + (threadIdx.x >> 6);
  int d = threadIdx.x & 63;
  unsigned short* qrow = qk + (size_t)t * 2048 + h * 64;
  unsigned short* krow = qrow + 1024;
  float q = bf2f(qrow[d]), k = bf2f(krow[d]);
  float qs = q * q, ks = k * k;
  for (int off = 32; off; off >>= 1) {
    qs += __shfl_xor(qs, off, 64);
    ks += __shfl_xor(ks, off, 64);
  }
  const void* qn = (t < 512) ? qn_c : qn_x;
  const void* kn = (t < 512) ? kn_c : kn_x;
  q = q * rsqrtf(qs * (1.0f / 64.0f) + 1e-6f) * loadE(qn, d, flag);
  k = k * rsqrtf(ks * (1.0f / 64.0f) + 1e-6f) * loadE(kn, d, flag);
  int j = d >> 1;
  float cv = loadE(freqs, (size_t)(t * 32 + j) * 2 + 0, flag);
  float sv = loadE(freqs, (size_t)(t * 32 + j) * 2 + 1, flag);
  float qo = __shfl_xor(q, 1, 64);
  float ko = __shfl_xor(k, 1, 64);
  float qn2, kn2;
  if ((d & 1) == 0) { qn2 = q * cv - qo * sv; kn2 = k * cv - ko * sv; }
  else              { qn2 = qo * sv + q * cv; kn2 = ko * sv + k * cv; }
  qrow[d] = f2bf(qn2);
  krow[d] = f2bf(kn2);
}

// ---------- MFMA flash attention (round-9 staging + mask skip) ----------
__global__ __launch_bounds__(256) void attn_kernel(const unsigned short* __restrict__ qk,
                                                   const unsigned short* __restrict__ vT,
                                                   unsigned short* __restrict__ y) {
  int id = blockIdx.x;
  int blk = (id & 256) ? (31 - (id & 31)) : (id & 31);
  int h = (id >> 5) & 15;
  int wv = threadIdx.x >> 6;
  int lane = threadIdx.x & 63;
  int qbase = blk * 64 + wv * 16;

  __shared__ __align__(16) unsigned short Ks[2 * 4096];  // [buf][key][64 d] swz
  __shared__ __align__(16) unsigned short Vs[2 * 4096];  // [buf][d][64 key] swz
  __shared__ __align__(16) unsigned short ps[4][16 * 72];

  const int c0 = wv * 64 + lane;
  const int r0 = c0 >> 3,         k0 = (c0 & 7) ^ (r0 & 7);
  const int r1 = (c0 + 256) >> 3, k1 = (c0 & 7) ^ (r1 & 7);
  unsigned short* kd0 = Ks + wv * 512;
  unsigned short* kd1 = Ks + 2048 + wv * 512;
  unsigned short* vd0 = Vs + wv * 512;
  unsigned short* vd1 = Vs + 2048 + wv * 512;
  const unsigned short* kgp0 = qk + 1024 + h * 64 + k0 * 8 + (size_t)r0 * 2048;
  const unsigned short* kgp1 = qk + 1024 + h * 64 + k1 * 8 + (size_t)r1 * 2048;
  const unsigned short* vgp0 = vT + (size_t)(h * 64 + r0) * 2048 + k0 * 8;
  const unsigned short* vgp1 = vT + (size_t)(h * 64 + r1) * 2048 + k1 * 8;
  auto stage = [&](int buf, int j0) {
    int bo = buf * 4096;
    gl16(kgp0 + (size_t)j0 * 2048, kd0 + bo);
    gl16(kgp1 + (size_t)j0 * 2048, kd1 + bo);
    gl16(vgp0 + j0, vd0 + bo);
    gl16(vgp1 + j0, vd1 + bo);
  };

  short8 qa[2];
  {
    int m = lane & 15, dj = (lane >> 4) * 8;
    const unsigned short* qp = qk + (size_t)(qbase + m) * 2048 + h * 64 + dj;
    qa[0] = *(const short8*)(qp);
    qa[1] = *(const short8*)(qp + 32);
  }
  floatx4 o[4] = {};
  float mrow[4] = {-1e30f, -1e30f, -1e30f, -1e30f};
  float lrow[4] = {0.f, 0.f, 0.f, 0.f};
  int ntiles = blk + 1;

  stage(0, 0);
  FBAR();
  for (int tile = 0; tile < ntiles; ++tile) {
    int j0 = tile * 64;
    if (tile + 1 < ntiles) stage((tile + 1) & 1, j0 + 64);
    const unsigned short* Kb = Ks + (tile & 1) * 4096;
    const unsigned short* Vb = Vs + (tile & 1) * 4096;
    floatx4 sacc[4];
    #pragma unroll
    for (int kg = 0; kg < 4; ++kg) {
      floatx4 z = {0.f, 0.f, 0.f, 0.f};
      #pragma unroll
      for (int kc = 0; kc < 2; ++kc) {
        int kr = kg * 16 + (lane & 15);
        int p = (kc * 4 + (lane >> 4)) ^ (kr & 7);
        short8 kb = *(const short8*)(Kb + kr * 64 + p * 8);
        z = __builtin_amdgcn_mfma_f32_16x16x32_bf16(qa[kc], kb, z, 0, 0, 0);
      }
      sacc[kg] = z;
    }
    // causal mask only needed on the diagonal tile (wave-uniform branch)
    if (tile == blk) {
      #pragma unroll
      for (int kg = 0; kg < 4; ++kg)
        #pragma unroll
        for (int r = 0; r < 4; ++r) {
          int key_g = j0 + kg * 16 + (lane & 15);
          int q_g = qbase + (lane >> 4) * 4 + r;
          float s = sacc[kg][r] * 0.125f;
          sacc[kg][r] = (key_g <= q_g) ? s : -1e30f;
        }
    } else {
      #pragma unroll
      for (int kg = 0; kg < 4; ++kg)
        #pragma unroll
        for (int r = 0; r < 4; ++r) sacc[kg][r] *= 0.125f;
    }
    #pragma unroll
    for (int r = 0; r < 4; ++r) {
      float mx = fmaxf(fmaxf(sacc[0][r], sacc[1][r]), fmaxf(sacc[2][r], sacc[3][r]));
      mx = fmaxf(mx, __shfl_xor(mx, 1, 64));
      mx = fmaxf(mx, __shfl_xor(mx, 2, 64));
      mx = fmaxf(mx, __shfl_xor(mx, 4, 64));
      mx = fmaxf(mx, __shfl_xor(mx, 8, 64));
      float mnew = fmaxf(mrow[r], mx);
      float al = __expf(mrow[r] - mnew);
      mrow[r] = mnew;
      float sum = 0.f;
      #pragma unroll
      for (int kg = 0; kg < 4; ++kg) {
        float p = __expf(sacc[kg][r] - mnew);
        sacc[kg][r] = p;
        sum += p;
      }
      sum += __shfl_xor(sum, 1, 64);
      sum += __shfl_xor(sum, 2, 64);
      sum += __shfl_xor(sum, 4, 64);
      sum += __shfl_xor(sum, 8, 64);
      lrow[r] = lrow[r] * al + sum;
      #pragma unroll
      for (int ni = 0; ni < 4; ++ni) o[ni][r] *= al;
    }
    unsigned short* pw = ps[wv];
    #pragma unroll
    for (int kg = 0; kg < 4; ++kg)
      #pragma unroll
      for (int r = 0; r < 4; ++r)
        pw[((lane >> 4) * 4 + r) * 72 + kg * 16 + (lane & 15)] = f2bf(sacc[kg][r]);
    asm volatile("s_waitcnt lgkmcnt(0)" ::: "memory");
    short8 pa[2];
    pa[0] = *(const short8*)(pw + (lane & 15) * 72 + (lane >> 4) * 8);
    pa[1] = *(const short8*)(pw + (lane & 15) * 72 + 32 + (lane >> 4) * 8);
    #pragma unroll
    for (int ni = 0; ni < 4; ++ni) {
      floatx4 z = o[ni];
      int dd = ni * 16 + (lane & 15);
      #pragma unroll
      for (int kc = 0; kc < 2; ++kc) {
        int p = (kc * 4 + (lane >> 4)) ^ (dd & 7);
        short8 vb = *(const short8*)(Vb + dd * 64 + p * 8);
        z = __builtin_amdgcn_mfma_f32_16x16x32_bf16(pa[kc], vb, z, 0, 0, 0);
      }
      o[ni] = z;
    }
    if (tile + 1 < ntiles) FBAR();
  }
  #pragma unroll
  for (int ni = 0; ni < 4; ++ni)
    #pragma unroll
    for (int r = 0; r < 4; ++r) {
      int q = qbase + (lane >> 4) * 4 + r;
      int dd = ni * 16 + (lane & 15);
      y[(size_t)q * 1024 + h * 64 + dd] = f2bf(o[ni][r] / lrow[r]);
    }
}

extern "C" void kernel_launch(void* const* d_in, const int* in_sizes, int n_in,
                              void* d_out, int out_size, void* d_ws, size_t ws_size,
                              hipStream_t stream) {
  const int L = 1536, S = 512, D = 1024, T = 2048, FF = 4096;
  const void* x        = d_in[0];
  const void* c        = d_in[1];
  const void* freqs    = d_in[2];
  const void* px_qk_w  = d_in[3];
  const void* px_qn    = d_in[4];
  const void* px_kn    = d_in[5];
  const void* px_v_w   = d_in[6];
  const void* px_v_b   = d_in[7];
  const void* pc_qk_w  = d_in[8];
  const void* pc_qn    = d_in[9];
  const void* pc_kn    = d_in[10];
  const void* pc_v_w   = d_in[11];
  const void* pc_v_b   = d_in[12];
  const void* p1_proj_w = d_in[13];
  const void* p1_proj_b = d_in[14];
  const void* p1_w1 = d_in[15];
  const void* p1_b1 = d_in[16];
  const void* p1_w3 = d_in[17];
  const void* p1_b3 = d_in[18];
  const void* p1_w2 = d_in[19];
  const void* p1_b2 = d_in[20];
  const void* p2_proj_w = d_in[21];
  const void* p2_proj_b = d_in[22];
  const void* p2_w1 = d_in[23];
  const void* p2_b1 = d_in[24];
  const void* p2_w3 = d_in[25];
  const void* p2_b3 = d_in[26];
  const void* p2_w2 = d_in[27];
  const void* p2_b2 = d_in[28];

  // Workspace map (MB from ws):
  //  0-4   hln -> ybuf -> h1c        4-12 qk / h1x      12-16 vT / h1x
  //  16-20 mid   20-21 midln_c   21 flag
  //  24-40 bf16 cache: qk_c qk_x v_c v_x pj1 pj2   (convw_A)
  //  40-72 P2 partials (after attn) -> convw_B fills w1/w3 cache -> P5 partials
  //  72-88 bf16 cache: w2p1 w2p2                   (convw_A)
  char* ws = (char*)d_ws;
  unsigned short* hln     = (unsigned short*)(ws);
  unsigned short* ybuf    = (unsigned short*)(ws);
  unsigned short* h1c     = (unsigned short*)(ws);
  unsigned short* qkbuf   = (unsigned short*)(ws + ((size_t)4  << 20));
  unsigned short* h1x     = (unsigned short*)(ws + ((size_t)4  << 20));
  unsigned short* vbufT   = (unsigned short*)(ws + ((size_t)12 << 20));
  unsigned short* mid     = (unsigned short*)(ws + ((size_t)16 << 20));
  unsigned short* midln_c = (unsigned short*)(ws + ((size_t)20 << 20));
  int*            flag    = (int*)(ws + ((size_t)21 << 20));
  unsigned short* midln_x = (unsigned short*)d_out;
  unsigned short* hlnx    = hln + (size_t)S * D;

  const bool conv = ws_size >= ((size_t)90 << 20);
  unsigned short* wbf = (unsigned short*)(ws + ((size_t)24 << 20));
  unsigned short* b_qk_c = wbf + 0;
  unsigned short* b_qk_x = wbf + 2097152;
  unsigned short* b_v_c  = wbf + 4194304;
  unsigned short* b_v_x  = wbf + 5242880;
  unsigned short* b_pj1  = wbf + 6291456;
  unsigned short* b_pj2  = wbf + 7340032;
  unsigned short* b_w1p1 = wbf + 8388608;   // 40-48 MB
  unsigned short* b_w1p2 = wbf + 12582912;  // 48-56
  unsigned short* b_w3p1 = wbf + 16777216;  // 56-64
  unsigned short* b_w3p2 = wbf + 20971520;  // 64-72
  unsigned short* b_w2p1 = wbf + 25165824;  // 72-80
  unsigned short* b_w2p2 = wbf + 29360128;  // 80-88
  float* part = (float*)(ws + ((size_t)40 << 20));  // 4 x 8MB (P2 then P5)

  detect_kernel<<<1, 64, 0, stream>>>((const unsigned int*)px_qn, flag);

  if (conv) {
    // convw_A: everything except w1/w3 (whose cache region hosts P2 partials first)
    CArgs ca = {};
    const void* insA[8]    = {pc_qk_w, px_qk_w, pc_v_w, px_v_w, p1_proj_w, p2_proj_w,
                              p1_w2, p2_w2};
    unsigned short* osA[8] = {b_qk_c, b_qk_x, b_v_c, b_v_x, b_pj1, b_pj2,
                              b_w2p1, b_w2p2};
    unsigned int cntA[8]   = {262144, 262144, 131072, 131072, 131072, 131072,
                              524288, 524288};
    unsigned int cum = 0;
    for (int i = 0; i < 8; ++i) { ca.in[i] = insA[i]; ca.out[i] = osA[i]; cum += cntA[i]; ca.cum[i] = cum; }
    for (int i = 8; i < 12; ++i) ca.cum[i] = 0x7FFFFFFFu;
    convw_kernel<<<1024, 256, 0, stream>>>(ca, flag);  // 2,097,152 chunks / 2048
  }

  ln_ext_kernel<<<T, 256, 0, stream>>>(c, x, hln, flag);

  // P1: QKV (4 descriptors). V descs (2,3) store TRANSPOSED into vbufT (tmask).
  {
    GArgs g = {};
    g.A[0] = hln;  g.bias[0] = nullptr; g.C[0] = qkbuf;                    g.mcum[0] = 4;  g.N[0] = 2048;
    g.A[1] = hlnx; g.bias[1] = nullptr; g.C[1] = qkbuf + (size_t)S * 2048; g.mcum[1] = 16; g.N[1] = 2048;
    g.A[2] = hln;  g.bias[2] = pc_v_b;  g.C[2] = vbufT; g.oo[2] = 0;       g.mcum[2] = 20; g.N[2] = 1024;
    g.A[3] = hlnx; g.bias[3] = px_v_b;  g.C[3] = vbufT; g.oo[3] = S;       g.mcum[3] = 32; g.N[3] = 1024;
    g.K = 1024; g.nd = 4; g.tmask = 0b1100;
    if (conv) {
      g.B[0] = b_qk_c; g.B[1] = b_qk_x; g.B[2] = b_v_c; g.B[3] = b_v_x;
      gemm_kernel<0, 0, 1, 1><<<dim3(16, 32), 256, 0, stream>>>(g, flag);
    } else {
      g.B[0] = pc_qk_w; g.B[1] = px_qk_w; g.B[2] = pc_v_w; g.B[3] = px_v_w;
      gemm_kernel<0, 0, 1, 0><<<dim3(16, 32), 256, 0, stream>>>(g, flag);
    }
  }
  rmsrope_kernel<<<dim3(T, 4), 256, 0, stream>>>(qkbuf, pc_qn, pc_kn, px_qn, px_kn, freqs, flag);
  attn_kernel<<<512, 256, 0, stream>>>(qkbuf, vbufT, ybuf);

  // P2: out-projection + external residual -> mid.
  // conv path: split-K=4 raw partials (grid 512 = full CU coverage; old grid 128
  // left half the CUs idle) + reduce_mid (bias + external res + bf16 pack).
  if (conv) {
    GArgs g = {};
    g.A[0] = ybuf;                  g.C[0] = mid; g.oo[0] = 0;             g.bias[0] = p2_proj_b; g.res[0] = c; g.mcum[0] = 4;  g.N[0] = 1024;
    g.A[1] = ybuf + (size_t)S * D;  g.C[1] = mid; g.oo[1] = (size_t)S * D; g.bias[1] = p1_proj_b; g.res[1] = x; g.mcum[1] = 16; g.N[1] = 1024;
    g.K = 1024; g.nd = 2;
    g.part = part;
    g.B[0] = b_pj2; g.B[1] = b_pj1;
    gemm_kernel<1, 3, 4, 1><<<dim3(8, 16, 4), 256, 0, stream>>>(g, flag);
    reduce_mid_kernel<<<2048, 256, 0, stream>>>(part, c, x, (const float*)p2_proj_b,
                                                (const float*)p1_proj_b, mid, flag);
    // convw_B: w1/w3 into the region P2's partials just vacated
    CArgs cb = {};
    const void* insB[4]    = {p1_w1, p2_w1, p1_w3, p2_w3};
    unsigned short* osB[4] = {b_w1p1, b_w1p2, b_w3p1, b_w3p2};
    unsigned int cum = 0;
    for (int i = 0; i < 4; ++i) { cb.in[i] = insB[i]; cb.out[i] = osB[i]; cum += 524288u; cb.cum[i] = cum; }
    for (int i = 4; i < 12; ++i) cb.cum[i] = 0x7FFFFFFFu;
    convw_kernel<<<1024, 256, 0, stream>>>(cb, flag);
  } else {
    GArgs g = {};
    g.A[0] = ybuf;                  g.bias[0] = p2_proj_b; g.res[0] = c; g.C[0] = mid;                  g.mcum[0] = 4;  g.N[0] = 1024;
    g.A[1] = ybuf + (size_t)S * D;  g.bias[1] = p1_proj_b; g.res[1] = x; g.C[1] = mid + (size_t)S * D;  g.mcum[1] = 16; g.N[1] = 1024;
    g.K = 1024; g.nd = 2;
    g.B[0] = p2_proj_w; g.B[1] = p1_proj_w;
    gemm_kernel<1, 0, 1, 0><<<dim3(8, 16), 256, 0, stream>>>(g, flag);
  }
  ln_mid_kernel<<<T, 256, 0, stream>>>(mid, midln_c, midln_x);

  // P3: W1 (x + c merged)
  {
    GArgs g = {};
    g.A[0] = midln_x; g.bias[0] = p1_b1; g.C[0] = h1x; g.mcum[0] = 12; g.N[0] = 4096;
    g.A[1] = midln_c; g.bias[1] = p2_b1; g.C[1] = h1c; g.mcum[1] = 16; g.N[1] = 4096;
    g.K = 1024; g.nd = 2;
    if (conv) {
      g.B[0] = b_w1p1; g.B[1] = b_w1p2;
      gemm_kernel<0, 0, 1, 1><<<dim3(32, 16), 256, 0, stream>>>(g, flag);
    } else {
      g.B[0] = p1_w1; g.B[1] = p2_w1;
      gemm_kernel<0, 0, 1, 0><<<dim3(32, 16), 256, 0, stream>>>(g, flag);
    }
  }
  // P4: W3 with fused silu(h1)*(acc+bias), in place
  {
    GArgs g = {};
    g.A[0] = midln_x; g.bias[0] = p1_b3; g.res[0] = h1x; g.C[0] = h1x; g.mcum[0] = 12; g.N[0] = 4096;
    g.A[1] = midln_c; g.bias[1] = p2_b3; g.res[1] = h1c; g.C[1] = h1c; g.mcum[1] = 16; g.N[1] = 4096;
    g.K = 1024; g.nd = 2;
    if (conv) {
      g.B[0] = b_w3p1; g.B[1] = b_w3p2;
      gemm_kernel<3, 0, 1, 1><<<dim3(32, 16), 256, 0, stream>>>(g, flag);
    } else {
      g.B[0] = p1_w3; g.B[1] = p2_w3;
      gemm_kernel<3, 0, 1, 0><<<dim3(32, 16), 256, 0, stream>>>(g, flag);
    }
  }
  // P5: W2 split-K=4. conv: raw fp32 partials + reduce. fallback: zero + atomics.
  if (conv) {
    GArgs g = {};
    g.A[0] = h1x; g.bias[0] = p1_b2; g.res[0] = mid + (size_t)S * D; g.C[0] = d_out; g.oo[0] = 0;             g.mcum[0] = 12; g.N[0] = 1024;
    g.A[1] = h1c; g.bias[1] = p2_b2; g.res[1] = mid;                 g.C[1] = d_out; g.oo[1] = (size_t)L * D; g.mcum[1] = 16; g.N[1] = 1024;
    g.K = 4096; g.nd = 2;
    g.part = part;
    g.B[0] = b_w2p1; g.B[1] = b_w2p2;
    gemm_kernel<4, 3, 4, 1><<<dim3(8, 16, 4), 256, 0, stream>>>(g, flag);
    reduce_kernel<<<2048, 256, 0, stream>>>(part, mid, p1_b2, p2_b2, (float*)d_out, flag);
  } else {
    zero_kernel<<<2048, 256, 0, stream>>>(d_out, out_size, flag);
    GArgs g = {};
    g.A[0] = h1x; g.bias[0] = p1_b2; g.res[0] = mid + (size_t)S * D; g.C[0] = d_out; g.oo[0] = 0;             g.mcum[0] = 12; g.N[0] = 1024;
    g.A[1] = h1c; g.bias[1] = p2_b2; g.res[1] = mid;                 g.C[1] = d_out; g.oo[1] = (size_t)L * D; g.mcum[1] = 16; g.N[1] = 1024;
    g.K = 4096; g.nd = 2;
    g.B[0] = p1_w2; g.B[1] = p2_w2;
    gemm_kernel<4, 2, 4, 0><<<dim3(8, 16, 4), 256, 0, stream>>>(g, flag);
  }
}